// Round 2
// baseline (1023.065 us; speedup 1.0000x reference)
//
#include <hip/hip_runtime.h>
#include <cstddef>

#define NRELS 8
#define EMB 128
#define HID 128
#define OUTD 256
#define HEADS 4
#define RANK 8
#define D2 512            // HEADS*HID, conv2 input dim
#define NEG_SLOPE 0.2f
#define LN_EPS 1e-5f

// ---------------- Generic tiled fp32 GEMM: C[M,N] = A[M,K] @ B[N,K]^T ----------------
// BM=BN=64, BK=32, 256 threads, 4x4 micro-tile. N,K must be multiples of 64/32; M guarded.
__global__ __launch_bounds__(256) void gemm_abt(const float* __restrict__ A,
    const float* __restrict__ B, float* __restrict__ C, int M, int N, int K) {
  __shared__ float As[32][64];
  __shared__ float Bs[32][64];
  const int tid = threadIdx.x;
  const int bm = blockIdx.y * 64;
  const int bn = blockIdx.x * 64;
  const int tx = tid & 15;
  const int ty = tid >> 4;
  const int lr = tid & 63;   // row within tile for loads
  const int lq = tid >> 6;   // 0..3 float4-slot along K
  float acc[4][4] = {};
  for (int k0 = 0; k0 < K; k0 += 32) {
#pragma unroll
    for (int s = 0; s < 2; ++s) {
      const int q = lq + s * 4;             // 0..7
      const int gm = bm + lr;
      float4 va = make_float4(0.f, 0.f, 0.f, 0.f);
      if (gm < M) va = *(const float4*)(A + (size_t)gm * K + k0 + q * 4);
      As[q * 4 + 0][lr] = va.x; As[q * 4 + 1][lr] = va.y;
      As[q * 4 + 2][lr] = va.z; As[q * 4 + 3][lr] = va.w;
      const int gn = bn + lr;
      float4 vb = *(const float4*)(B + (size_t)gn * K + k0 + q * 4);
      Bs[q * 4 + 0][lr] = vb.x; Bs[q * 4 + 1][lr] = vb.y;
      Bs[q * 4 + 2][lr] = vb.z; Bs[q * 4 + 3][lr] = vb.w;
    }
    __syncthreads();
#pragma unroll
    for (int kk = 0; kk < 32; ++kk) {
      float a[4], b[4];
#pragma unroll
      for (int i2 = 0; i2 < 4; ++i2) { a[i2] = As[kk][ty * 4 + i2]; b[i2] = Bs[kk][tx * 4 + i2]; }
#pragma unroll
      for (int i2 = 0; i2 < 4; ++i2)
#pragma unroll
        for (int j2 = 0; j2 < 4; ++j2)
          acc[i2][j2] = fmaf(a[i2], b[j2], acc[i2][j2]);
    }
    __syncthreads();
  }
#pragma unroll
  for (int i2 = 0; i2 < 4; ++i2) {
    const int gm = bm + ty * 4 + i2;
    if (gm >= M) continue;
#pragma unroll
    for (int j2 = 0; j2 < 4; ++j2)
      C[(size_t)gm * N + bn + tx * 4 + j2] = acc[i2][j2];
  }
}

// dst[(r*RANK+k)*D + d] = src[r*(D*RANK) + d*RANK + k]  (LoRA weight re-layout)
__global__ void expand_lora(const float* __restrict__ src, float* __restrict__ dst,
                            int R, int D) {
  int idx = blockIdx.x * blockDim.x + threadIdx.x;
  int total = R * RANK * D;
  if (idx >= total) return;
  int d = idx % D;
  int rk = idx / D;
  int k = rk % RANK;
  int r = rk / RANK;
  dst[idx] = src[(size_t)r * D * RANK + (size_t)d * RANK + k];
}

// Matt1[rk*4+h] = sum_c M1[rk*512 + h*128 + c] * attR[h*128 + c]
__global__ void matt1_kernel(const float* __restrict__ M1, const float* __restrict__ attR,
                             float* __restrict__ Matt1) {
  int idx = threadIdx.x;  // 256 threads = 64 rk * 4 h
  int h = idx & 3, rk = idx >> 2;
  float s = 0.f;
  for (int c = 0; c < HID; ++c) s = fmaf(M1[(size_t)rk * D2 + h * HID + c], attR[h * HID + c], s);
  Matt1[rk * 4 + h] = s;
}

// Matt2[rk] = sum_c M2[rk*256 + c] * attR[c]
__global__ void matt2_kernel(const float* __restrict__ M2, const float* __restrict__ attR,
                             float* __restrict__ Matt2) {
  int rk = threadIdx.x;  // 64 threads
  float s = 0.f;
  for (int c = 0; c < OUTD; ++c) s = fmaf(M2[(size_t)rk * OUTD + c], attR[c], s);
  Matt2[rk] = s;
}

// al[n*H+h] = Z[n, h*C:...]·attL ; ar likewise
__global__ void rowdot(const float* __restrict__ Z, const float* __restrict__ attL,
                       const float* __restrict__ attR, float* __restrict__ al,
                       float* __restrict__ ar, int Nn, int H, int C) {
  int idx = blockIdx.x * blockDim.x + threadIdx.x;
  if (idx >= Nn * H) return;
  int h = idx % H, n = idx / H;
  const float* z = Z + (size_t)n * H * C + (size_t)h * C;
  const float* L = attL + (size_t)h * C;
  const float* R = attR + (size_t)h * C;
  float sl = 0.f, sr = 0.f;
  for (int c = 0; c < C; ++c) { float zv = z[c]; sl = fmaf(zv, L[c], sl); sr = fmaf(zv, R[c], sr); }
  al[idx] = sl;
  ar[idx] = sr;
}

// Layer-1 attention logits: ex1[e,h]=exp(leaky(alpha)), den1[(rt*N+i)*4+h] += ex
__global__ void edge_alpha1(const int* __restrict__ ji, const int* __restrict__ ii,
                            const int* __restrict__ et, const float* __restrict__ P1,
                            const float* __restrict__ al1, const float* __restrict__ ar1,
                            const float* __restrict__ relb1, const float* __restrict__ Matt1,
                            float* __restrict__ ex1, float* __restrict__ den1, int E, int Nn) {
  int e = blockIdx.x * blockDim.x + threadIdx.x;
  if (e >= E) return;
  int j = ji[e], i = ii[e], rt = et[e];
  float low[RANK];
#pragma unroll
  for (int k = 0; k < RANK; ++k) low[k] = P1[(size_t)j * 64 + rt * RANK + k];
#pragma unroll
  for (int h = 0; h < HEADS; ++h) {
    float a = al1[i * 4 + h] + ar1[j * 4 + h] + relb1[rt * 4 + h];
#pragma unroll
    for (int k = 0; k < RANK; ++k) a = fmaf(low[k], Matt1[(rt * RANK + k) * 4 + h], a);
    a = (a > 0.f) ? a : NEG_SLOPE * a;
    float x = expf(a);
    ex1[(size_t)e * 4 + h] = x;
    atomicAdd(&den1[((size_t)rt * Nn + i) * 4 + h], x);
  }
}

// Layer-1 aggregation: out1[i] += w_h * (z1[j] + low @ M1[rt])
__global__ __launch_bounds__(256) void edge_agg1(const int* __restrict__ ji,
    const int* __restrict__ ii, const int* __restrict__ et, const float* __restrict__ P1,
    const float* __restrict__ M1, const float* __restrict__ ex1, const float* __restrict__ den1,
    const float* __restrict__ z1, float* __restrict__ out1, int Nn) {
  int e = blockIdx.x;
  int t = threadIdx.x;
  __shared__ float s_low[RANK];
  __shared__ float s_w[HEADS];
  int j = ji[e], i = ii[e], rt = et[e];
  if (t < RANK) s_low[t] = P1[(size_t)j * 64 + rt * RANK + t];
  if (t >= RANK && t < RANK + HEADS) {
    int h = t - RANK;
    s_w[h] = ex1[(size_t)e * 4 + h] / den1[((size_t)rt * Nn + i) * 4 + h];
  }
  __syncthreads();
#pragma unroll
  for (int cc = 0; cc < 2; ++cc) {
    int c = t + cc * 256;
    float v = z1[(size_t)j * D2 + c];
#pragma unroll
    for (int k = 0; k < RANK; ++k) v = fmaf(s_low[k], M1[(size_t)(rt * RANK + k) * D2 + c], v);
    atomicAdd(&out1[(size_t)i * D2 + c], s_w[c >> 7] * v);
  }
}

// x1 = elu(out1 + bias1), in place
__global__ void elu_bias(float* __restrict__ h1, const float* __restrict__ bias1, int total) {
  int idx = blockIdx.x * blockDim.x + threadIdx.x;
  if (idx >= total) return;
  float v = h1[idx] + bias1[idx % D2];
  h1[idx] = (v > 0.f) ? v : expm1f(v);
}

// Layer-2 attention logits (1 head)
__global__ void edge_alpha2(const int* __restrict__ ji, const int* __restrict__ ii,
                            const int* __restrict__ et, const float* __restrict__ P2,
                            const float* __restrict__ al2, const float* __restrict__ ar2,
                            const float* __restrict__ relb2, const float* __restrict__ Matt2,
                            float* __restrict__ ex2, float* __restrict__ den2, int E, int Nn) {
  int e = blockIdx.x * blockDim.x + threadIdx.x;
  if (e >= E) return;
  int j = ji[e], i = ii[e], rt = et[e];
  float a = al2[i] + ar2[j] + relb2[rt];
#pragma unroll
  for (int k = 0; k < RANK; ++k)
    a = fmaf(P2[(size_t)j * 64 + rt * RANK + k], Matt2[rt * RANK + k], a);
  a = (a > 0.f) ? a : NEG_SLOPE * a;
  float x = expf(a);
  ex2[e] = x;
  atomicAdd(&den2[(size_t)rt * Nn + i], x);
}

// Layer-2 aggregation: o2[i] += w * (z2[j] + low @ M2[rt])   (o2 pre-loaded with residual GEMM)
__global__ __launch_bounds__(256) void edge_agg2(const int* __restrict__ ji,
    const int* __restrict__ ii, const int* __restrict__ et, const float* __restrict__ P2,
    const float* __restrict__ M2, const float* __restrict__ ex2, const float* __restrict__ den2,
    const float* __restrict__ z2, float* __restrict__ o2, int Nn) {
  int e = blockIdx.x;
  int t = threadIdx.x;
  __shared__ float s_low[RANK];
  __shared__ float s_w;
  int j = ji[e], i = ii[e], rt = et[e];
  if (t < RANK) s_low[t] = P2[(size_t)j * 64 + rt * RANK + t];
  if (t == RANK) s_w = ex2[e] / den2[(size_t)rt * Nn + i];
  __syncthreads();
  int c = t;
  float v = z2[(size_t)j * OUTD + c];
#pragma unroll
  for (int k = 0; k < RANK; ++k) v = fmaf(s_low[k], M2[(size_t)(rt * RANK + k) * OUTD + c], v);
  atomicAdd(&o2[(size_t)i * OUTD + c], s_w * v);
}

// Final: y = LN(o2 + bias2 + res_b) * ln_g + ln_b    (o2 already holds agg2 + x0@res_W^T)
__global__ __launch_bounds__(256) void final_ln(const float* __restrict__ o2,
    const float* __restrict__ bias2, const float* __restrict__ res_b,
    const float* __restrict__ ln_g, const float* __restrict__ ln_b,
    float* __restrict__ y) {
  int n = blockIdx.x;
  int t = threadIdx.x;
  __shared__ float red[256];
  float v = o2[(size_t)n * OUTD + t] + bias2[t] + res_b[t];
  red[t] = v;
  __syncthreads();
  for (int s = 128; s > 0; s >>= 1) { if (t < s) red[t] += red[t + s]; __syncthreads(); }
  float mu = red[0] / OUTD;
  __syncthreads();
  float d = v - mu;
  red[t] = d * d;
  __syncthreads();
  for (int s = 128; s > 0; s >>= 1) { if (t < s) red[t] += red[t + s]; __syncthreads(); }
  float var = red[0] / OUTD;
  __syncthreads();
  y[(size_t)n * OUTD + t] = d * rsqrtf(var + LN_EPS) * ln_g[t] + ln_b[t];
}

extern "C" void kernel_launch(void* const* d_in, const int* in_sizes, int n_in,
                              void* d_out, int out_size, void* d_ws, size_t ws_size,
                              hipStream_t stream) {
  const float* x0     = (const float*)d_in[0];
  const float* A1     = (const float*)d_in[1];
  const float* B1     = (const float*)d_in[2];
  const float* W1     = (const float*)d_in[3];
  const float* attL1  = (const float*)d_in[4];
  const float* attR1  = (const float*)d_in[5];
  const float* relb1  = (const float*)d_in[6];
  const float* bias1  = (const float*)d_in[7];
  const float* A2     = (const float*)d_in[8];
  const float* B2     = (const float*)d_in[9];
  const float* W2     = (const float*)d_in[10];
  const float* attL2  = (const float*)d_in[11];
  const float* attR2  = (const float*)d_in[12];
  const float* relb2  = (const float*)d_in[13];
  const float* bias2  = (const float*)d_in[14];
  const float* res_W  = (const float*)d_in[15];
  const float* res_b  = (const float*)d_in[16];
  const float* ln_g   = (const float*)d_in[17];
  const float* ln_b   = (const float*)d_in[18];
  const int*   eidx   = (const int*)d_in[19];
  const int*   etype  = (const int*)d_in[20];
  float* out = (float*)d_out;

  const int Nn = in_sizes[0] / EMB;     // 30000
  const int E  = in_sizes[20];          // 150000
  const int* ji = eidx;                 // edge_index[0] = source
  const int* ii = eidx + E;             // edge_index[1] = target

  // ---- workspace carve-up (floats) ----
  float* w = (float*)d_ws;
  size_t off = 0;
  float* z1    = w + off; off += (size_t)Nn * D2;        // 15.36M
  float* h1    = w + off; off += (size_t)Nn * D2;        // out1 -> x1
  float* z2    = w + off; off += (size_t)Nn * OUTD;      // 7.68M
  float* o2    = w + off; off += (size_t)Nn * OUTD;      // residual + agg2
  float* P1    = w + off; off += (size_t)Nn * 64;
  float* P2    = w + off; off += (size_t)Nn * 64;
  float* M1    = w + off; off += 64 * D2;
  float* M2    = w + off; off += 64 * OUTD;
  float* Amat1 = w + off; off += 64 * EMB;
  float* Bmat1 = w + off; off += 64 * EMB;
  float* Amat2 = w + off; off += 64 * D2;
  float* Bmat2 = w + off; off += 64 * D2;
  float* Matt1 = w + off; off += 64 * 4;
  float* Matt2 = w + off; off += 64;
  float* al1   = w + off; off += (size_t)Nn * 4;
  float* ar1   = w + off; off += (size_t)Nn * 4;
  float* al2   = w + off; off += (size_t)Nn;
  float* ar2   = w + off; off += (size_t)Nn;
  float* ex1   = w + off; off += (size_t)E * 4;
  float* ex2   = w + off; off += (size_t)E;
  float* den1  = w + off; off += (size_t)NRELS * Nn * 4;
  float* den2  = w + off; off += (size_t)NRELS * Nn;
  (void)ws_size; (void)n_in; (void)out_size;

  const int MB = (Nn + 63) / 64;  // 469 row-blocks

  // 1) LoRA weight re-layouts
  expand_lora<<<(64 * EMB + 255) / 256, 256, 0, stream>>>(A1, Amat1, NRELS, EMB);
  expand_lora<<<(64 * EMB + 255) / 256, 256, 0, stream>>>(B1, Bmat1, NRELS, EMB);
  expand_lora<<<(64 * D2 + 255) / 256, 256, 0, stream>>>(A2, Amat2, NRELS, D2);
  expand_lora<<<(64 * D2 + 255) / 256, 256, 0, stream>>>(B2, Bmat2, NRELS, D2);

  // 2) M1 = Amat1 @ W1^T [64,512];  M2 = Amat2 @ W2^T [64,256]
  gemm_abt<<<dim3(D2 / 64, 1), 256, 0, stream>>>(Amat1, W1, M1, 64, D2, EMB);
  gemm_abt<<<dim3(OUTD / 64, 1), 256, 0, stream>>>(Amat2, W2, M2, 64, OUTD, D2);

  // 3) Matt folds
  matt1_kernel<<<1, 256, 0, stream>>>(M1, attR1, Matt1);
  matt2_kernel<<<1, 64, 0, stream>>>(M2, attR2, Matt2);

  // 4) Layer-1 node GEMMs
  gemm_abt<<<dim3(D2 / 64, MB), 256, 0, stream>>>(x0, W1, z1, Nn, D2, EMB);
  gemm_abt<<<dim3(1, MB), 256, 0, stream>>>(x0, Bmat1, P1, Nn, 64, EMB);

  // 5) Per-node attention dots
  rowdot<<<(Nn * 4 + 255) / 256, 256, 0, stream>>>(z1, attL1, attR1, al1, ar1, Nn, HEADS, HID);

  // 6) zero accumulators
  hipMemsetAsync(den1, 0, (size_t)NRELS * Nn * 4 * sizeof(float), stream);
  hipMemsetAsync(h1, 0, (size_t)Nn * D2 * sizeof(float), stream);

  // 7) Layer-1 edge softmax + aggregation
  edge_alpha1<<<(E + 255) / 256, 256, 0, stream>>>(ji, ii, etype, P1, al1, ar1, relb1, Matt1,
                                                   ex1, den1, E, Nn);
  edge_agg1<<<E, 256, 0, stream>>>(ji, ii, etype, P1, M1, ex1, den1, z1, h1, Nn);

  // 8) ELU + bias
  elu_bias<<<((size_t)Nn * D2 + 255) / 256, 256, 0, stream>>>(h1, bias1, Nn * D2);

  // 9) Layer-2 node GEMMs + residual GEMM (into o2, before atomics)
  gemm_abt<<<dim3(OUTD / 64, MB), 256, 0, stream>>>(h1, W2, z2, Nn, OUTD, D2);
  gemm_abt<<<dim3(1, MB), 256, 0, stream>>>(h1, Bmat2, P2, Nn, 64, D2);
  gemm_abt<<<dim3(OUTD / 64, MB), 256, 0, stream>>>(x0, res_W, o2, Nn, OUTD, EMB);

  // 10) Layer-2 attention dots
  rowdot<<<(Nn + 255) / 256, 256, 0, stream>>>(z2, attL2, attR2, al2, ar2, Nn, 1, OUTD);

  // 11) Layer-2 edge softmax + aggregation
  hipMemsetAsync(den2, 0, (size_t)NRELS * Nn * sizeof(float), stream);
  edge_alpha2<<<(E + 255) / 256, 256, 0, stream>>>(ji, ii, etype, P2, al2, ar2, relb2, Matt2,
                                                   ex2, den2, E, Nn);
  edge_agg2<<<E, 256, 0, stream>>>(ji, ii, etype, P2, M2, ex2, den2, z2, o2, Nn);

  // 12) bias2 + res_b + LayerNorm -> out
  final_ln<<<Nn, 256, 0, stream>>>(o2, bias2, res_b, ln_g, ln_b, out);
}

// Round 4
// 854.534 us; speedup vs baseline: 1.1972x; 1.1972x over previous
//
#include <hip/hip_runtime.h>
#include <cstddef>

#define NRELS 8
#define EMB 128
#define HID 128
#define OUTD 256
#define HEADS 4
#define RANK 8
#define D2 512            // HEADS*HID, conv2 input dim
#define NEG_SLOPE 0.2f
#define LN_EPS 1e-5f

// ---------------- Generic tiled fp32 GEMM: C[M,N] = A[M,K] @ B[N,K]^T ----------------
__global__ __launch_bounds__(256) void gemm_abt(const float* __restrict__ A,
    const float* __restrict__ B, float* __restrict__ C, int M, int N, int K) {
  __shared__ float As[32][64];
  __shared__ float Bs[32][64];
  const int tid = threadIdx.x;
  const int bm = blockIdx.y * 64;
  const int bn = blockIdx.x * 64;
  const int tx = tid & 15;
  const int ty = tid >> 4;
  const int lr = tid & 63;
  const int lq = tid >> 6;
  float acc[4][4] = {};
  for (int k0 = 0; k0 < K; k0 += 32) {
#pragma unroll
    for (int s = 0; s < 2; ++s) {
      const int q = lq + s * 4;
      const int gm = bm + lr;
      float4 va = make_float4(0.f, 0.f, 0.f, 0.f);
      if (gm < M) va = *(const float4*)(A + (size_t)gm * K + k0 + q * 4);
      As[q * 4 + 0][lr] = va.x; As[q * 4 + 1][lr] = va.y;
      As[q * 4 + 2][lr] = va.z; As[q * 4 + 3][lr] = va.w;
      const int gn = bn + lr;
      float4 vb = *(const float4*)(B + (size_t)gn * K + k0 + q * 4);
      Bs[q * 4 + 0][lr] = vb.x; Bs[q * 4 + 1][lr] = vb.y;
      Bs[q * 4 + 2][lr] = vb.z; Bs[q * 4 + 3][lr] = vb.w;
    }
    __syncthreads();
#pragma unroll
    for (int kk = 0; kk < 32; ++kk) {
      float a[4], b[4];
#pragma unroll
      for (int i2 = 0; i2 < 4; ++i2) { a[i2] = As[kk][ty * 4 + i2]; b[i2] = Bs[kk][tx * 4 + i2]; }
#pragma unroll
      for (int i2 = 0; i2 < 4; ++i2)
#pragma unroll
        for (int j2 = 0; j2 < 4; ++j2)
          acc[i2][j2] = fmaf(a[i2], b[j2], acc[i2][j2]);
    }
    __syncthreads();
  }
#pragma unroll
  for (int i2 = 0; i2 < 4; ++i2) {
    const int gm = bm + ty * 4 + i2;
    if (gm >= M) continue;
#pragma unroll
    for (int j2 = 0; j2 < 4; ++j2)
      C[(size_t)gm * N + bn + tx * 4 + j2] = acc[i2][j2];
  }
}

// dst[(r*RANK+k)*D + d] = src[r*(D*RANK) + d*RANK + k]
__global__ void expand_lora(const float* __restrict__ src, float* __restrict__ dst,
                            int R, int D) {
  int idx = blockIdx.x * blockDim.x + threadIdx.x;
  int total = R * RANK * D;
  if (idx >= total) return;
  int d = idx % D;
  int rk = idx / D;
  int k = rk % RANK;
  int r = rk / RANK;
  dst[idx] = src[(size_t)r * D * RANK + (size_t)d * RANK + k];
}

__global__ void matt1_kernel(const float* __restrict__ M1, const float* __restrict__ attR,
                             float* __restrict__ Matt1) {
  int idx = threadIdx.x;
  int h = idx & 3, rk = idx >> 2;
  float s = 0.f;
  for (int c = 0; c < HID; ++c) s = fmaf(M1[(size_t)rk * D2 + h * HID + c], attR[h * HID + c], s);
  Matt1[rk * 4 + h] = s;
}

__global__ void matt2_kernel(const float* __restrict__ M2, const float* __restrict__ attR,
                             float* __restrict__ Matt2) {
  int rk = threadIdx.x;
  float s = 0.f;
  for (int c = 0; c < OUTD; ++c) s = fmaf(M2[(size_t)rk * OUTD + c], attR[c], s);
  Matt2[rk] = s;
}

__global__ void rowdot(const float* __restrict__ Z, const float* __restrict__ attL,
                       const float* __restrict__ attR, float* __restrict__ al,
                       float* __restrict__ ar, int Nn, int H, int C) {
  int idx = blockIdx.x * blockDim.x + threadIdx.x;
  if (idx >= Nn * H) return;
  int h = idx % H, n = idx / H;
  const float* z = Z + (size_t)n * H * C + (size_t)h * C;
  const float* L = attL + (size_t)h * C;
  const float* R = attR + (size_t)h * C;
  float sl = 0.f, sr = 0.f;
  for (int c = 0; c < C; ++c) { float zv = z[c]; sl = fmaf(zv, L[c], sl); sr = fmaf(zv, R[c], sr); }
  al[idx] = sl;
  ar[idx] = sr;
}

// ---------------- CSR build over target node i ----------------
__global__ void hist_kernel(const int* __restrict__ ii, int* __restrict__ deg, int E) {
  int e = blockIdx.x * blockDim.x + threadIdx.x;
  if (e < E) atomicAdd(&deg[ii[e]], 1);
}

// single-block exclusive scan (chunked Hillis-Steele)
__global__ __launch_bounds__(1024) void exscan_kernel(const int* __restrict__ deg,
                                                      int* __restrict__ rowstart, int n) {
  __shared__ int s[1024];
  __shared__ int carry;
  int t = threadIdx.x;
  if (t == 0) carry = 0;
  __syncthreads();
  for (int base = 0; base < n; base += 1024) {
    int v = (base + t < n) ? deg[base + t] : 0;
    s[t] = v;
    __syncthreads();
    for (int o = 1; o < 1024; o <<= 1) {
      int x = (t >= o) ? s[t - o] : 0;
      __syncthreads();
      s[t] += x;
      __syncthreads();
    }
    if (base + t < n) rowstart[base + t] = carry + s[t] - v;
    if (t == 1023) s[0] = carry + s[1023];
    __syncthreads();
    if (t == 0) carry = s[0];
    __syncthreads();
  }
  if (t == 0) rowstart[n] = carry;
}

__global__ void scatter_kernel(const int* __restrict__ ii, const int* __restrict__ rowstart,
                               int* __restrict__ cursor, int* __restrict__ eid, int E) {
  int e = blockIdx.x * blockDim.x + threadIdx.x;
  if (e >= E) return;
  int i = ii[e];
  int p = atomicAdd(&cursor[i], 1);
  eid[rowstart[i] + p] = e;
}

// ---------------- Layer-1 edge logits (no atomics) ----------------
__global__ void edge_alpha1(const int* __restrict__ ji, const int* __restrict__ ii,
                            const int* __restrict__ et, const float* __restrict__ P1,
                            const float* __restrict__ al1, const float* __restrict__ ar1,
                            const float* __restrict__ relb1, const float* __restrict__ Matt1,
                            float* __restrict__ ex1, int E) {
  int e = blockIdx.x * blockDim.x + threadIdx.x;
  if (e >= E) return;
  int j = ji[e], i = ii[e], rt = et[e];
  float low[RANK];
#pragma unroll
  for (int k = 0; k < RANK; ++k) low[k] = P1[(size_t)j * 64 + rt * RANK + k];
#pragma unroll
  for (int h = 0; h < HEADS; ++h) {
    float a = al1[i * 4 + h] + ar1[j * 4 + h] + relb1[rt * 4 + h];
#pragma unroll
    for (int k = 0; k < RANK; ++k) a = fmaf(low[k], Matt1[(rt * RANK + k) * 4 + h], a);
    a = (a > 0.f) ? a : NEG_SLOPE * a;
    ex1[(size_t)e * 4 + h] = expf(a);
  }
}

// ---------------- Layer-1 CSR gather: softmax + aggregate + bias + ELU ----------------
__global__ __launch_bounds__(256) void node_agg1(const int* __restrict__ ji,
    const int* __restrict__ et, const int* __restrict__ rowstart, const int* __restrict__ eid,
    const float* __restrict__ P1, const float* __restrict__ M1, const float* __restrict__ ex1,
    const float* __restrict__ z1, const float* __restrict__ bias1,
    float* __restrict__ h1out, int Nn) {
  int i = blockIdx.x;
  int t = threadIdx.x;
  int s0 = rowstart[i], s1 = rowstart[i + 1];
  int deg = s1 - s0;
  __shared__ float s_den[NRELS * HEADS];
  if (t < NRELS * HEADS) s_den[t] = 0.f;
  __syncthreads();
  for (int p = t; p < deg * HEADS; p += 256) {
    int e = eid[s0 + (p >> 2)];
    int h = p & 3;
    atomicAdd(&s_den[et[e] * HEADS + h], ex1[(size_t)e * 4 + h]);
  }
  __syncthreads();
  const int c0 = t, c1 = t + 256;
  const int ha = c0 >> 7, hb = c1 >> 7;
  float acc0 = 0.f, acc1 = 0.f;
  for (int p = 0; p < deg; ++p) {
    int e = eid[s0 + p];
    int j = ji[e], rt = et[e];
    float w0 = ex1[(size_t)e * 4 + ha] / s_den[rt * 4 + ha];
    float w1 = ex1[(size_t)e * 4 + hb] / s_den[rt * 4 + hb];
    float low[RANK];
#pragma unroll
    for (int k = 0; k < RANK; ++k) low[k] = P1[(size_t)j * 64 + rt * 8 + k];
    float v0 = z1[(size_t)j * D2 + c0];
    float v1 = z1[(size_t)j * D2 + c1];
#pragma unroll
    for (int k = 0; k < RANK; ++k) {
      const float* m = M1 + (size_t)(rt * 8 + k) * D2;
      v0 = fmaf(low[k], m[c0], v0);
      v1 = fmaf(low[k], m[c1], v1);
    }
    acc0 = fmaf(w0, v0, acc0);
    acc1 = fmaf(w1, v1, acc1);
  }
  float r0 = acc0 + bias1[c0];
  float r1 = acc1 + bias1[c1];
  h1out[(size_t)i * D2 + c0] = r0 > 0.f ? r0 : expm1f(r0);
  h1out[(size_t)i * D2 + c1] = r1 > 0.f ? r1 : expm1f(r1);
}

// ---------------- Layer-2 edge logits (1 head, no atomics) ----------------
__global__ void edge_alpha2(const int* __restrict__ ji, const int* __restrict__ ii,
                            const int* __restrict__ et, const float* __restrict__ P2,
                            const float* __restrict__ al2, const float* __restrict__ ar2,
                            const float* __restrict__ relb2, const float* __restrict__ Matt2,
                            float* __restrict__ ex2, int E) {
  int e = blockIdx.x * blockDim.x + threadIdx.x;
  if (e >= E) return;
  int j = ji[e], i = ii[e], rt = et[e];
  float a = al2[i] + ar2[j] + relb2[rt];
#pragma unroll
  for (int k = 0; k < RANK; ++k)
    a = fmaf(P2[(size_t)j * 64 + rt * RANK + k], Matt2[rt * RANK + k], a);
  a = (a > 0.f) ? a : NEG_SLOPE * a;
  ex2[e] = expf(a);
}

// ---------------- Layer-2 CSR gather + residual + bias + LayerNorm -> out ----------------
__global__ __launch_bounds__(256) void node_agg2(const int* __restrict__ ji,
    const int* __restrict__ et, const int* __restrict__ rowstart, const int* __restrict__ eid,
    const float* __restrict__ P2, const float* __restrict__ M2, const float* __restrict__ ex2,
    const float* __restrict__ z2, const float* __restrict__ res,
    const float* __restrict__ bias2, const float* __restrict__ res_b,
    const float* __restrict__ ln_g, const float* __restrict__ ln_b,
    float* __restrict__ y, int Nn) {
  int i = blockIdx.x;
  int t = threadIdx.x;
  int s0 = rowstart[i], s1 = rowstart[i + 1];
  int deg = s1 - s0;
  __shared__ float s_den[NRELS];
  __shared__ float red[256];
  if (t < NRELS) s_den[t] = 0.f;
  __syncthreads();
  for (int p = t; p < deg; p += 256) {
    int e = eid[s0 + p];
    atomicAdd(&s_den[et[e]], ex2[e]);
  }
  __syncthreads();
  float acc = 0.f;
  for (int p = 0; p < deg; ++p) {
    int e = eid[s0 + p];
    int j = ji[e], rt = et[e];
    float wgt = ex2[e] / s_den[rt];
    float low[RANK];
#pragma unroll
    for (int k = 0; k < RANK; ++k) low[k] = P2[(size_t)j * 64 + rt * 8 + k];
    float v = z2[(size_t)j * OUTD + t];
#pragma unroll
    for (int k = 0; k < RANK; ++k)
      v = fmaf(low[k], M2[(size_t)(rt * 8 + k) * OUTD + t], v);
    acc = fmaf(wgt, v, acc);
  }
  float v = acc + res[(size_t)i * OUTD + t] + bias2[t] + res_b[t];
  red[t] = v;
  __syncthreads();
  for (int s = 128; s > 0; s >>= 1) { if (t < s) red[t] += red[t + s]; __syncthreads(); }
  float mu = red[0] / OUTD;
  __syncthreads();
  float d = v - mu;
  red[t] = d * d;
  __syncthreads();
  for (int s = 128; s > 0; s >>= 1) { if (t < s) red[t] += red[t + s]; __syncthreads(); }
  float var = red[0] / OUTD;
  y[(size_t)i * OUTD + t] = d * rsqrtf(var + LN_EPS) * ln_g[t] + ln_b[t];
}

extern "C" void kernel_launch(void* const* d_in, const int* in_sizes, int n_in,
                              void* d_out, int out_size, void* d_ws, size_t ws_size,
                              hipStream_t stream) {
  const float* x0     = (const float*)d_in[0];
  const float* A1     = (const float*)d_in[1];
  const float* B1     = (const float*)d_in[2];
  const float* W1     = (const float*)d_in[3];
  const float* attL1  = (const float*)d_in[4];
  const float* attR1  = (const float*)d_in[5];
  const float* relb1  = (const float*)d_in[6];
  const float* bias1  = (const float*)d_in[7];
  const float* A2     = (const float*)d_in[8];
  const float* B2     = (const float*)d_in[9];
  const float* W2     = (const float*)d_in[10];
  const float* attL2  = (const float*)d_in[11];
  const float* attR2  = (const float*)d_in[12];
  const float* relb2  = (const float*)d_in[13];
  const float* bias2  = (const float*)d_in[14];
  const float* res_W  = (const float*)d_in[15];
  const float* res_b  = (const float*)d_in[16];
  const float* ln_g   = (const float*)d_in[17];
  const float* ln_b   = (const float*)d_in[18];
  const int*   eidx   = (const int*)d_in[19];
  const int*   etype  = (const int*)d_in[20];
  float* out = (float*)d_out;

  const int Nn = in_sizes[0] / EMB;     // 30000
  const int E  = in_sizes[20];          // 150000
  const int* ji = eidx;                 // edge_index[0] = source
  const int* ii = eidx + E;             // edge_index[1] = target

  // ---- workspace carve-up (floats) ----
  float* w = (float*)d_ws;
  size_t off = 0;
  float* z1    = w + off; off += (size_t)Nn * D2;
  float* h1    = w + off; off += (size_t)Nn * D2;
  float* z2    = w + off; off += (size_t)Nn * OUTD;
  float* o2    = w + off; off += (size_t)Nn * OUTD;      // residual GEMM result
  float* P1    = w + off; off += (size_t)Nn * 64;
  float* P2    = w + off; off += (size_t)Nn * 64;
  float* M1    = w + off; off += 64 * D2;
  float* M2    = w + off; off += 64 * OUTD;
  float* Amat1 = w + off; off += 64 * EMB;
  float* Bmat1 = w + off; off += 64 * EMB;
  float* Amat2 = w + off; off += 64 * D2;
  float* Bmat2 = w + off; off += 64 * D2;
  float* Matt1 = w + off; off += 64 * 4;
  float* Matt2 = w + off; off += 64;
  float* al1   = w + off; off += (size_t)Nn * 4;
  float* ar1   = w + off; off += (size_t)Nn * 4;
  float* al2   = w + off; off += (size_t)Nn;
  float* ar2   = w + off; off += (size_t)Nn;
  float* ex1   = w + off; off += (size_t)E * 4;
  float* ex2   = w + off; off += (size_t)E;
  // ---- CSR (int) ----
  int* ideg     = (int*)(w + off); off += (size_t)Nn;
  int* rowstart = (int*)(w + off); off += (size_t)Nn + 1;
  int* cursor   = (int*)(w + off); off += (size_t)Nn;
  int* eid      = (int*)(w + off); off += (size_t)E;
  (void)ws_size; (void)n_in; (void)out_size;

  const int MB = (Nn + 63) / 64;

  // 0) CSR build (same graph both layers)
  (void)hipMemsetAsync(ideg, 0, (size_t)Nn * sizeof(int), stream);
  (void)hipMemsetAsync(cursor, 0, (size_t)Nn * sizeof(int), stream);
  hist_kernel<<<(E + 255) / 256, 256, 0, stream>>>(ii, ideg, E);
  exscan_kernel<<<1, 1024, 0, stream>>>(ideg, rowstart, Nn);
  scatter_kernel<<<(E + 255) / 256, 256, 0, stream>>>(ii, rowstart, cursor, eid, E);

  // 1) LoRA weight re-layouts
  expand_lora<<<(64 * EMB + 255) / 256, 256, 0, stream>>>(A1, Amat1, NRELS, EMB);
  expand_lora<<<(64 * EMB + 255) / 256, 256, 0, stream>>>(B1, Bmat1, NRELS, EMB);
  expand_lora<<<(64 * D2 + 255) / 256, 256, 0, stream>>>(A2, Amat2, NRELS, D2);
  expand_lora<<<(64 * D2 + 255) / 256, 256, 0, stream>>>(B2, Bmat2, NRELS, D2);

  // 2) M1 = Amat1 @ W1^T ; M2 = Amat2 @ W2^T
  gemm_abt<<<dim3(D2 / 64, 1), 256, 0, stream>>>(Amat1, W1, M1, 64, D2, EMB);
  gemm_abt<<<dim3(OUTD / 64, 1), 256, 0, stream>>>(Amat2, W2, M2, 64, OUTD, D2);

  // 3) Matt folds
  matt1_kernel<<<1, 256, 0, stream>>>(M1, attR1, Matt1);
  matt2_kernel<<<1, 64, 0, stream>>>(M2, attR2, Matt2);

  // 4) Layer-1 node GEMMs
  gemm_abt<<<dim3(D2 / 64, MB), 256, 0, stream>>>(x0, W1, z1, Nn, D2, EMB);
  gemm_abt<<<dim3(1, MB), 256, 0, stream>>>(x0, Bmat1, P1, Nn, 64, EMB);

  // 5) attention dots
  rowdot<<<(Nn * 4 + 255) / 256, 256, 0, stream>>>(z1, attL1, attR1, al1, ar1, Nn, HEADS, HID);

  // 6) Layer-1 edge logits + CSR gather (fused softmax/agg/bias/ELU)
  edge_alpha1<<<(E + 255) / 256, 256, 0, stream>>>(ji, ii, etype, P1, al1, ar1, relb1, Matt1,
                                                   ex1, E);
  node_agg1<<<Nn, 256, 0, stream>>>(ji, etype, rowstart, eid, P1, M1, ex1, z1, bias1, h1, Nn);

  // 7) Layer-2 node GEMMs + residual GEMM
  gemm_abt<<<dim3(OUTD / 64, MB), 256, 0, stream>>>(h1, W2, z2, Nn, OUTD, D2);
  gemm_abt<<<dim3(1, MB), 256, 0, stream>>>(h1, Bmat2, P2, Nn, 64, D2);
  gemm_abt<<<dim3(OUTD / 64, MB), 256, 0, stream>>>(x0, res_W, o2, Nn, OUTD, EMB);

  // 8) Layer-2 attention dots
  rowdot<<<(Nn + 255) / 256, 256, 0, stream>>>(z2, attL2, attR2, al2, ar2, Nn, 1, OUTD);

  // 9) Layer-2 edge logits + CSR gather (fused softmax/agg/residual/LN)
  edge_alpha2<<<(E + 255) / 256, 256, 0, stream>>>(ji, ii, etype, P2, al2, ar2, relb2, Matt2,
                                                   ex2, E);
  node_agg2<<<Nn, 256, 0, stream>>>(ji, etype, rowstart, eid, P2, M2, ex2, z2, o2,
                                    bias2, res_b, ln_g, ln_b, out, Nn);
}

// Round 5
// 852.521 us; speedup vs baseline: 1.2000x; 1.0024x over previous
//
#include <hip/hip_runtime.h>
#include <cstddef>

#define NRELS 8
#define EMB 128
#define HID 128
#define OUTD 256
#define HEADS 4
#define RANK 8
#define D2 512            // HEADS*HID, conv2 input dim
#define NEG_SLOPE 0.2f
#define LN_EPS 1e-5f

typedef short bf16x8 __attribute__((ext_vector_type(8)));   // 8 bf16 in 4 VGPRs
typedef float f32x4 __attribute__((ext_vector_type(4)));

__device__ __forceinline__ unsigned short f2bf(float f) {   // RNE
  union { float f; unsigned u; } v; v.f = f;
  unsigned u = v.u;
  return (unsigned short)((u + 0x7fffu + ((u >> 16) & 1u)) >> 16);
}

// ---------------- bf16 MFMA GEMM: C[M,N] = A[M,K] @ B[N,K]^T ----------------
// grid = (M/16, N/64), block = 256 (4 waves). Wave w does n-tile blockIdx.y*4+w.
// A,B bf16 (row-major, K contiguous, K%32==0), C fp32.
__global__ __launch_bounds__(256) void gemm_bf16(const unsigned short* __restrict__ A,
    const unsigned short* __restrict__ B, float* __restrict__ C, int M, int N, int K) {
  const int wave = threadIdx.x >> 6;
  const int lane = threadIdx.x & 63;
  const int mt = blockIdx.x;
  const int nt = blockIdx.y * 4 + wave;
  const int r16 = lane & 15;
  const int quad = lane >> 4;
  const unsigned short* Ap = A + (size_t)(mt * 16 + r16) * K + quad * 8;
  const unsigned short* Bp = B + (size_t)(nt * 16 + r16) * K + quad * 8;
  f32x4 acc = {0.f, 0.f, 0.f, 0.f};
#pragma unroll 4
  for (int k0 = 0; k0 < K; k0 += 32) {
    bf16x8 a = *(const bf16x8*)(Ap + k0);
    bf16x8 b = *(const bf16x8*)(Bp + k0);
    acc = __builtin_amdgcn_mfma_f32_16x16x32_bf16(a, b, acc, 0, 0, 0);
  }
  // C/D layout: col = lane&15, row = quad*4 + reg   [m89-verified]
#pragma unroll
  for (int r = 0; r < 4; ++r)
    C[(size_t)(mt * 16 + quad * 4 + r) * N + nt * 16 + r16] = acc[r];
}

// ---------------- fp32 tiled GEMM (only for tiny M1/M2 precompute) ----------------
__global__ __launch_bounds__(256) void gemm_abt(const float* __restrict__ A,
    const float* __restrict__ B, float* __restrict__ C, int M, int N, int K) {
  __shared__ float As[32][64];
  __shared__ float Bs[32][64];
  const int tid = threadIdx.x;
  const int bm = blockIdx.y * 64;
  const int bn = blockIdx.x * 64;
  const int tx = tid & 15;
  const int ty = tid >> 4;
  const int lr = tid & 63;
  const int lq = tid >> 6;
  float acc[4][4] = {};
  for (int k0 = 0; k0 < K; k0 += 32) {
#pragma unroll
    for (int s = 0; s < 2; ++s) {
      const int q = lq + s * 4;
      const int gm = bm + lr;
      float4 va = make_float4(0.f, 0.f, 0.f, 0.f);
      if (gm < M) va = *(const float4*)(A + (size_t)gm * K + k0 + q * 4);
      As[q * 4 + 0][lr] = va.x; As[q * 4 + 1][lr] = va.y;
      As[q * 4 + 2][lr] = va.z; As[q * 4 + 3][lr] = va.w;
      const int gn = bn + lr;
      float4 vb = *(const float4*)(B + (size_t)gn * K + k0 + q * 4);
      Bs[q * 4 + 0][lr] = vb.x; Bs[q * 4 + 1][lr] = vb.y;
      Bs[q * 4 + 2][lr] = vb.z; Bs[q * 4 + 3][lr] = vb.w;
    }
    __syncthreads();
#pragma unroll
    for (int kk = 0; kk < 32; ++kk) {
      float a[4], b[4];
#pragma unroll
      for (int i2 = 0; i2 < 4; ++i2) { a[i2] = As[kk][ty * 4 + i2]; b[i2] = Bs[kk][tx * 4 + i2]; }
#pragma unroll
      for (int i2 = 0; i2 < 4; ++i2)
#pragma unroll
        for (int j2 = 0; j2 < 4; ++j2)
          acc[i2][j2] = fmaf(a[i2], b[j2], acc[i2][j2]);
    }
    __syncthreads();
  }
#pragma unroll
  for (int i2 = 0; i2 < 4; ++i2) {
    const int gm = bm + ty * 4 + i2;
    if (gm >= M) continue;
#pragma unroll
    for (int j2 = 0; j2 < 4; ++j2)
      C[(size_t)gm * N + bn + tx * 4 + j2] = acc[i2][j2];
  }
}

__global__ void to_bf16(const float* __restrict__ in, unsigned short* __restrict__ out, int n) {
  int i = blockIdx.x * 256 + threadIdx.x;
  if (i < n) out[i] = f2bf(in[i]);
}

// dst[(r*RANK+k)*D + d] = src[r*(D*RANK) + d*RANK + k]   (fp32, for A-side)
__global__ void expand_lora(const float* __restrict__ src, float* __restrict__ dst,
                            int R, int D) {
  int idx = blockIdx.x * blockDim.x + threadIdx.x;
  int total = R * RANK * D;
  if (idx >= total) return;
  int d = idx % D;
  int rk = idx / D;
  int k = rk % RANK;
  int r = rk / RANK;
  dst[idx] = src[(size_t)r * D * RANK + (size_t)d * RANK + k];
}

// bf16 variant (for B-side feeding MFMA)
__global__ void expand_lora_bf16(const float* __restrict__ src, unsigned short* __restrict__ dst,
                                 int R, int D) {
  int idx = blockIdx.x * blockDim.x + threadIdx.x;
  int total = R * RANK * D;
  if (idx >= total) return;
  int d = idx % D;
  int rk = idx / D;
  int k = rk % RANK;
  int r = rk / RANK;
  dst[idx] = f2bf(src[(size_t)r * D * RANK + (size_t)d * RANK + k]);
}

__global__ void matt1_kernel(const float* __restrict__ M1, const float* __restrict__ attR,
                             float* __restrict__ Matt1) {
  int idx = threadIdx.x;
  int h = idx & 3, rk = idx >> 2;
  float s = 0.f;
  for (int c = 0; c < HID; ++c) s = fmaf(M1[(size_t)rk * D2 + h * HID + c], attR[h * HID + c], s);
  Matt1[rk * 4 + h] = s;
}

__global__ void matt2_kernel(const float* __restrict__ M2, const float* __restrict__ attR,
                             float* __restrict__ Matt2) {
  int rk = threadIdx.x;
  float s = 0.f;
  for (int c = 0; c < OUTD; ++c) s = fmaf(M2[(size_t)rk * OUTD + c], attR[c], s);
  Matt2[rk] = s;
}

__global__ void rowdot(const float* __restrict__ Z, const float* __restrict__ attL,
                       const float* __restrict__ attR, float* __restrict__ al,
                       float* __restrict__ ar, int Nn, int H, int C) {
  int idx = blockIdx.x * blockDim.x + threadIdx.x;
  if (idx >= Nn * H) return;
  int h = idx % H, n = idx / H;
  const float* z = Z + (size_t)n * H * C + (size_t)h * C;
  const float* L = attL + (size_t)h * C;
  const float* R = attR + (size_t)h * C;
  float sl = 0.f, sr = 0.f;
  for (int c = 0; c < C; ++c) { float zv = z[c]; sl = fmaf(zv, L[c], sl); sr = fmaf(zv, R[c], sr); }
  al[idx] = sl;
  ar[idx] = sr;
}

// ---------------- CSR build over target node i ----------------
__global__ void hist_kernel(const int* __restrict__ ii, int* __restrict__ deg, int E) {
  int e = blockIdx.x * blockDim.x + threadIdx.x;
  if (e < E) atomicAdd(&deg[ii[e]], 1);
}

__global__ __launch_bounds__(1024) void exscan_kernel(const int* __restrict__ deg,
                                                      int* __restrict__ rowstart, int n) {
  __shared__ int s[1024];
  __shared__ int carry;
  int t = threadIdx.x;
  if (t == 0) carry = 0;
  __syncthreads();
  for (int base = 0; base < n; base += 1024) {
    int v = (base + t < n) ? deg[base + t] : 0;
    s[t] = v;
    __syncthreads();
    for (int o = 1; o < 1024; o <<= 1) {
      int x = (t >= o) ? s[t - o] : 0;
      __syncthreads();
      s[t] += x;
      __syncthreads();
    }
    if (base + t < n) rowstart[base + t] = carry + s[t] - v;
    if (t == 1023) s[0] = carry + s[1023];
    __syncthreads();
    if (t == 0) carry = s[0];
    __syncthreads();
  }
  if (t == 0) rowstart[n] = carry;
}

__global__ void scatter_kernel(const int* __restrict__ ii, const int* __restrict__ rowstart,
                               int* __restrict__ cursor, int* __restrict__ eid, int E) {
  int e = blockIdx.x * blockDim.x + threadIdx.x;
  if (e >= E) return;
  int i = ii[e];
  int p = atomicAdd(&cursor[i], 1);
  eid[rowstart[i] + p] = e;
}

// ---------------- Layer-1 edge logits ----------------
__global__ void edge_alpha1(const int* __restrict__ ji, const int* __restrict__ ii,
                            const int* __restrict__ et, const float* __restrict__ P1,
                            const float* __restrict__ al1, const float* __restrict__ ar1,
                            const float* __restrict__ relb1, const float* __restrict__ Matt1,
                            float* __restrict__ ex1, int E) {
  int e = blockIdx.x * blockDim.x + threadIdx.x;
  if (e >= E) return;
  int j = ji[e], i = ii[e], rt = et[e];
  float low[RANK];
#pragma unroll
  for (int k = 0; k < RANK; ++k) low[k] = P1[(size_t)j * 64 + rt * RANK + k];
#pragma unroll
  for (int h = 0; h < HEADS; ++h) {
    float a = al1[i * 4 + h] + ar1[j * 4 + h] + relb1[rt * 4 + h];
#pragma unroll
    for (int k = 0; k < RANK; ++k) a = fmaf(low[k], Matt1[(rt * RANK + k) * 4 + h], a);
    a = (a > 0.f) ? a : NEG_SLOPE * a;
    ex1[(size_t)e * 4 + h] = expf(a);
  }
}

// ---------------- Layer-1 CSR gather: softmax + aggregate + bias + ELU -> bf16 h1 ----------------
__global__ __launch_bounds__(256) void node_agg1(const int* __restrict__ ji,
    const int* __restrict__ et, const int* __restrict__ rowstart, const int* __restrict__ eid,
    const float* __restrict__ P1, const float* __restrict__ M1, const float* __restrict__ ex1,
    const float* __restrict__ z1, const float* __restrict__ bias1,
    unsigned short* __restrict__ h1out, int Nn) {
  int i = blockIdx.x;
  int t = threadIdx.x;
  int s0 = rowstart[i], s1 = rowstart[i + 1];
  int deg = s1 - s0;
  __shared__ float s_den[NRELS * HEADS];
  if (t < NRELS * HEADS) s_den[t] = 0.f;
  __syncthreads();
  for (int p = t; p < deg * HEADS; p += 256) {
    int e = eid[s0 + (p >> 2)];
    int h = p & 3;
    atomicAdd(&s_den[et[e] * HEADS + h], ex1[(size_t)e * 4 + h]);
  }
  __syncthreads();
  const int c0 = t, c1 = t + 256;
  const int ha = c0 >> 7, hb = c1 >> 7;
  float acc0 = 0.f, acc1 = 0.f;
  for (int p = 0; p < deg; ++p) {
    int e = eid[s0 + p];
    int j = ji[e], rt = et[e];
    float w0 = ex1[(size_t)e * 4 + ha] / s_den[rt * 4 + ha];
    float w1 = ex1[(size_t)e * 4 + hb] / s_den[rt * 4 + hb];
    float low[RANK];
#pragma unroll
    for (int k = 0; k < RANK; ++k) low[k] = P1[(size_t)j * 64 + rt * 8 + k];
    float v0 = z1[(size_t)j * D2 + c0];
    float v1 = z1[(size_t)j * D2 + c1];
#pragma unroll
    for (int k = 0; k < RANK; ++k) {
      const float* m = M1 + (size_t)(rt * 8 + k) * D2;
      v0 = fmaf(low[k], m[c0], v0);
      v1 = fmaf(low[k], m[c1], v1);
    }
    acc0 = fmaf(w0, v0, acc0);
    acc1 = fmaf(w1, v1, acc1);
  }
  float r0 = acc0 + bias1[c0];
  float r1 = acc1 + bias1[c1];
  h1out[(size_t)i * D2 + c0] = f2bf(r0 > 0.f ? r0 : expm1f(r0));
  h1out[(size_t)i * D2 + c1] = f2bf(r1 > 0.f ? r1 : expm1f(r1));
}

// ---------------- Layer-2 edge logits ----------------
__global__ void edge_alpha2(const int* __restrict__ ji, const int* __restrict__ ii,
                            const int* __restrict__ et, const float* __restrict__ P2,
                            const float* __restrict__ al2, const float* __restrict__ ar2,
                            const float* __restrict__ relb2, const float* __restrict__ Matt2,
                            float* __restrict__ ex2, int E) {
  int e = blockIdx.x * blockDim.x + threadIdx.x;
  if (e >= E) return;
  int j = ji[e], i = ii[e], rt = et[e];
  float a = al2[i] + ar2[j] + relb2[rt];
#pragma unroll
  for (int k = 0; k < RANK; ++k)
    a = fmaf(P2[(size_t)j * 64 + rt * RANK + k], Matt2[rt * RANK + k], a);
  a = (a > 0.f) ? a : NEG_SLOPE * a;
  ex2[e] = expf(a);
}

// ---------------- Layer-2 CSR gather + residual + bias + LayerNorm -> out ----------------
__global__ __launch_bounds__(256) void node_agg2(const int* __restrict__ ji,
    const int* __restrict__ et, const int* __restrict__ rowstart, const int* __restrict__ eid,
    const float* __restrict__ P2, const float* __restrict__ M2, const float* __restrict__ ex2,
    const float* __restrict__ z2, const float* __restrict__ res,
    const float* __restrict__ bias2, const float* __restrict__ res_b,
    const float* __restrict__ ln_g, const float* __restrict__ ln_b,
    float* __restrict__ y, int Nn) {
  int i = blockIdx.x;
  int t = threadIdx.x;
  int s0 = rowstart[i], s1 = rowstart[i + 1];
  int deg = s1 - s0;
  __shared__ float s_den[NRELS];
  __shared__ float red[256];
  if (t < NRELS) s_den[t] = 0.f;
  __syncthreads();
  for (int p = t; p < deg; p += 256) {
    int e = eid[s0 + p];
    atomicAdd(&s_den[et[e]], ex2[e]);
  }
  __syncthreads();
  float acc = 0.f;
  for (int p = 0; p < deg; ++p) {
    int e = eid[s0 + p];
    int j = ji[e], rt = et[e];
    float wgt = ex2[e] / s_den[rt];
    float low[RANK];
#pragma unroll
    for (int k = 0; k < RANK; ++k) low[k] = P2[(size_t)j * 64 + rt * 8 + k];
    float v = z2[(size_t)j * OUTD + t];
#pragma unroll
    for (int k = 0; k < RANK; ++k)
      v = fmaf(low[k], M2[(size_t)(rt * 8 + k) * OUTD + t], v);
    acc = fmaf(wgt, v, acc);
  }
  float v = acc + res[(size_t)i * OUTD + t] + bias2[t] + res_b[t];
  red[t] = v;
  __syncthreads();
  for (int s = 128; s > 0; s >>= 1) { if (t < s) red[t] += red[t + s]; __syncthreads(); }
  float mu = red[0] / OUTD;
  __syncthreads();
  float d = v - mu;
  red[t] = d * d;
  __syncthreads();
  for (int s = 128; s > 0; s >>= 1) { if (t < s) red[t] += red[t + s]; __syncthreads(); }
  float var = red[0] / OUTD;
  y[(size_t)i * OUTD + t] = d * rsqrtf(var + LN_EPS) * ln_g[t] + ln_b[t];
}

extern "C" void kernel_launch(void* const* d_in, const int* in_sizes, int n_in,
                              void* d_out, int out_size, void* d_ws, size_t ws_size,
                              hipStream_t stream) {
  const float* x0     = (const float*)d_in[0];
  const float* A1     = (const float*)d_in[1];
  const float* B1     = (const float*)d_in[2];
  const float* W1     = (const float*)d_in[3];
  const float* attL1  = (const float*)d_in[4];
  const float* attR1  = (const float*)d_in[5];
  const float* relb1  = (const float*)d_in[6];
  const float* bias1  = (const float*)d_in[7];
  const float* A2     = (const float*)d_in[8];
  const float* B2     = (const float*)d_in[9];
  const float* W2     = (const float*)d_in[10];
  const float* attL2  = (const float*)d_in[11];
  const float* attR2  = (const float*)d_in[12];
  const float* relb2  = (const float*)d_in[13];
  const float* bias2  = (const float*)d_in[14];
  const float* res_W  = (const float*)d_in[15];
  const float* res_b  = (const float*)d_in[16];
  const float* ln_g   = (const float*)d_in[17];
  const float* ln_b   = (const float*)d_in[18];
  const int*   eidx   = (const int*)d_in[19];
  const int*   etype  = (const int*)d_in[20];
  float* out = (float*)d_out;

  const int Nn = in_sizes[0] / EMB;     // 30000
  const int E  = in_sizes[20];          // 150000
  const int* ji = eidx;
  const int* ii = eidx + E;

  // ---- workspace carve-up (float units; bf16 arrays placed on 4-float boundaries) ----
  float* w = (float*)d_ws;
  size_t off = 0;
  float* z1    = w + off; off += (size_t)Nn * D2;        // fp32 MFMA output
  float* z2    = w + off; off += (size_t)Nn * OUTD;
  float* o2    = w + off; off += (size_t)Nn * OUTD;      // residual GEMM result
  float* P1    = w + off; off += (size_t)Nn * 64;
  float* P2    = w + off; off += (size_t)Nn * 64;
  float* M1    = w + off; off += 64 * D2;
  float* M2    = w + off; off += 64 * OUTD;
  float* Amat1 = w + off; off += 64 * EMB;
  float* Amat2 = w + off; off += 64 * D2;
  float* Matt1 = w + off; off += 64 * 4;
  float* Matt2 = w + off; off += 64;
  float* al1   = w + off; off += (size_t)Nn * 4;
  float* ar1   = w + off; off += (size_t)Nn * 4;
  float* al2   = w + off; off += (size_t)Nn;
  float* ar2   = w + off; off += (size_t)Nn;
  float* ex1   = w + off; off += (size_t)E * 4;
  float* ex2   = w + off; off += (size_t)E;
  // bf16 arrays (element counts all multiples of 8 -> stay 16B aligned)
  unsigned short* x0b    = (unsigned short*)(w + off); off += (size_t)Nn * EMB / 2;
  unsigned short* h1b    = (unsigned short*)(w + off); off += (size_t)Nn * D2 / 2;
  unsigned short* W1b    = (unsigned short*)(w + off); off += (size_t)D2 * EMB / 2;
  unsigned short* W2b    = (unsigned short*)(w + off); off += (size_t)OUTD * D2 / 2;
  unsigned short* resWb  = (unsigned short*)(w + off); off += (size_t)OUTD * EMB / 2;
  unsigned short* Bmat1b = (unsigned short*)(w + off); off += (size_t)64 * EMB / 2;
  unsigned short* Bmat2b = (unsigned short*)(w + off); off += (size_t)64 * D2 / 2;
  // ints last (Nn+1 breaks alignment for anything after)
  int* ideg     = (int*)(w + off); off += (size_t)Nn;
  int* rowstart = (int*)(w + off); off += (size_t)Nn + 1;
  int* cursor   = (int*)(w + off); off += (size_t)Nn;
  int* eid      = (int*)(w + off); off += (size_t)E;
  (void)ws_size; (void)n_in; (void)out_size;

  const int MT = Nn / 16;   // 1875 m-tiles

  // 0) CSR build
  (void)hipMemsetAsync(ideg, 0, (size_t)Nn * sizeof(int), stream);
  (void)hipMemsetAsync(cursor, 0, (size_t)Nn * sizeof(int), stream);
  hist_kernel<<<(E + 255) / 256, 256, 0, stream>>>(ii, ideg, E);
  exscan_kernel<<<1, 1024, 0, stream>>>(ideg, rowstart, Nn);
  scatter_kernel<<<(E + 255) / 256, 256, 0, stream>>>(ii, rowstart, cursor, eid, E);

  // 1) LoRA re-layouts: A-side fp32 (feeds fp32 M-GEMM), B-side bf16 (feeds MFMA)
  expand_lora<<<(64 * EMB + 255) / 256, 256, 0, stream>>>(A1, Amat1, NRELS, EMB);
  expand_lora<<<(64 * D2 + 255) / 256, 256, 0, stream>>>(A2, Amat2, NRELS, D2);
  expand_lora_bf16<<<(64 * EMB + 255) / 256, 256, 0, stream>>>(B1, Bmat1b, NRELS, EMB);
  expand_lora_bf16<<<(64 * D2 + 255) / 256, 256, 0, stream>>>(B2, Bmat2b, NRELS, D2);

  // 2) weight/input bf16 conversions
  to_bf16<<<(Nn * EMB + 255) / 256, 256, 0, stream>>>(x0, x0b, Nn * EMB);
  to_bf16<<<(D2 * EMB + 255) / 256, 256, 0, stream>>>(W1, W1b, D2 * EMB);
  to_bf16<<<(OUTD * D2 + 255) / 256, 256, 0, stream>>>(W2, W2b, OUTD * D2);
  to_bf16<<<(OUTD * EMB + 255) / 256, 256, 0, stream>>>(res_W, resWb, OUTD * EMB);

  // 3) M1 = Amat1 @ W1^T ; M2 = Amat2 @ W2^T  (fp32, tiny)
  gemm_abt<<<dim3(D2 / 64, 1), 256, 0, stream>>>(Amat1, W1, M1, 64, D2, EMB);
  gemm_abt<<<dim3(OUTD / 64, 1), 256, 0, stream>>>(Amat2, W2, M2, 64, OUTD, D2);
  matt1_kernel<<<1, 256, 0, stream>>>(M1, attR1, Matt1);
  matt2_kernel<<<1, 64, 0, stream>>>(M2, attR2, Matt2);

  // 4) Layer-1 node GEMMs (bf16 MFMA): z1 = x0@W1^T, P1 = x0@Bmat1^T
  gemm_bf16<<<dim3(MT, D2 / 64), 256, 0, stream>>>(x0b, W1b, z1, Nn, D2, EMB);
  gemm_bf16<<<dim3(MT, 1), 256, 0, stream>>>(x0b, Bmat1b, P1, Nn, 64, EMB);

  // 5) attention dots
  rowdot<<<(Nn * 4 + 255) / 256, 256, 0, stream>>>(z1, attL1, attR1, al1, ar1, Nn, HEADS, HID);

  // 6) Layer-1 edge logits + CSR gather (writes h1 as bf16)
  edge_alpha1<<<(E + 255) / 256, 256, 0, stream>>>(ji, ii, etype, P1, al1, ar1, relb1, Matt1,
                                                   ex1, E);
  node_agg1<<<Nn, 256, 0, stream>>>(ji, etype, rowstart, eid, P1, M1, ex1, z1, bias1, h1b, Nn);

  // 7) Layer-2 node GEMMs + residual (bf16 MFMA)
  gemm_bf16<<<dim3(MT, OUTD / 64), 256, 0, stream>>>(h1b, W2b, z2, Nn, OUTD, D2);
  gemm_bf16<<<dim3(MT, 1), 256, 0, stream>>>(h1b, Bmat2b, P2, Nn, 64, D2);
  gemm_bf16<<<dim3(MT, OUTD / 64), 256, 0, stream>>>(x0b, resWb, o2, Nn, OUTD, EMB);

  // 8) Layer-2 attention dots
  rowdot<<<(Nn + 255) / 256, 256, 0, stream>>>(z2, attL2, attR2, al2, ar2, Nn, 1, OUTD);

  // 9) Layer-2 edge logits + CSR gather (fused residual/bias/LN)
  edge_alpha2<<<(E + 255) / 256, 256, 0, stream>>>(ji, ii, etype, P2, al2, ar2, relb2, Matt2,
                                                   ex2, E);
  node_agg2<<<Nn, 256, 0, stream>>>(ji, etype, rowstart, eid, P2, M2, ex2, z2, o2,
                                    bias2, res_b, ln_g, ln_b, out, Nn);
}

// Round 6
// 698.933 us; speedup vs baseline: 1.4638x; 1.2197x over previous
//
#include <hip/hip_runtime.h>
#include <cstddef>

#define NRELS 8
#define EMB 128
#define HID 128
#define OUTD 256
#define HEADS 4
#define RANK 8
#define D2 512            // HEADS*HID, conv2 input dim
#define NEG_SLOPE 0.2f
#define LN_EPS 1e-5f

typedef short bf16x8 __attribute__((ext_vector_type(8)));   // 8 bf16 in 4 VGPRs
typedef float f32x4 __attribute__((ext_vector_type(4)));

__device__ __forceinline__ unsigned short f2bf(float f) {   // RNE
  union { float f; unsigned u; } v; v.f = f;
  unsigned u = v.u;
  return (unsigned short)((u + 0x7fffu + ((u >> 16) & 1u)) >> 16);
}

// ---------------- LDS-tiled bf16 MFMA GEMM: C[M,N] = A[M,K] @ B[N,K]^T ----------------
// grid = (ceil(M/64), N/64), block = 256 = 2x2 waves, each wave a 32x32 tile
// (4 independent 16x16x32 MFMA accumulators). K%32==0, N%64==0; M guarded.
// LDS rows padded to 40 bf16 (80 B) to break bank-conflict strides.
__global__ __launch_bounds__(256) void gemm_bf16t(const unsigned short* __restrict__ A,
    const unsigned short* __restrict__ B, float* __restrict__ C, int M, int N, int K) {
  __shared__ unsigned short As[64][40];
  __shared__ unsigned short Bs[64][40];
  const int tid = threadIdx.x;
  const int wave = tid >> 6;
  const int lane = tid & 63;
  const int wm = wave & 1;          // wave M half
  const int wn = wave >> 1;         // wave N half
  const int r16 = lane & 15;
  const int quad = lane >> 4;
  const int bm = blockIdx.x * 64;
  const int bn = blockIdx.y * 64;
  // staging: thread t loads 8 bf16 (16 B) at row t>>2, k-chunk t&3 (4 threads/row = 64 B)
  const int srow = tid >> 2;
  const int schunk = tid & 3;
  int arow = bm + srow; if (arow >= M) arow = M - 1;   // clamp; C-store is guarded
  const unsigned short* Ag = A + (size_t)arow * K + schunk * 8;
  const unsigned short* Bg = B + (size_t)(bn + srow) * K + schunk * 8;
  f32x4 acc[2][2] = {};
  for (int k0 = 0; k0 < K; k0 += 32) {
    bf16x8 av = *(const bf16x8*)(Ag + k0);
    bf16x8 bv = *(const bf16x8*)(Bg + k0);
    __syncthreads();                 // protect previous iteration's reads
    *(bf16x8*)(&As[srow][schunk * 8]) = av;
    *(bf16x8*)(&Bs[srow][schunk * 8]) = bv;
    __syncthreads();
    bf16x8 af0 = *(const bf16x8*)(&As[wm * 32 + r16][quad * 8]);
    bf16x8 af1 = *(const bf16x8*)(&As[wm * 32 + 16 + r16][quad * 8]);
    bf16x8 bf0 = *(const bf16x8*)(&Bs[wn * 32 + r16][quad * 8]);
    bf16x8 bf1 = *(const bf16x8*)(&Bs[wn * 32 + 16 + r16][quad * 8]);
    acc[0][0] = __builtin_amdgcn_mfma_f32_16x16x32_bf16(af0, bf0, acc[0][0], 0, 0, 0);
    acc[0][1] = __builtin_amdgcn_mfma_f32_16x16x32_bf16(af0, bf1, acc[0][1], 0, 0, 0);
    acc[1][0] = __builtin_amdgcn_mfma_f32_16x16x32_bf16(af1, bf0, acc[1][0], 0, 0, 0);
    acc[1][1] = __builtin_amdgcn_mfma_f32_16x16x32_bf16(af1, bf1, acc[1][1], 0, 0, 0);
  }
  // C/D layout: col = lane&15, row = quad*4 + reg   [m89-verified]
#pragma unroll
  for (int mi = 0; mi < 2; ++mi)
#pragma unroll
    for (int ni = 0; ni < 2; ++ni)
#pragma unroll
      for (int r = 0; r < 4; ++r) {
        int row = bm + wm * 32 + mi * 16 + quad * 4 + r;
        if (row < M)
          C[(size_t)row * N + bn + wn * 32 + ni * 16 + r16] = acc[mi][ni][r];
      }
}

// ---------------- fp32 tiled GEMM (only for tiny M1/M2 precompute) ----------------
__global__ __launch_bounds__(256) void gemm_abt(const float* __restrict__ A,
    const float* __restrict__ B, float* __restrict__ C, int M, int N, int K) {
  __shared__ float As[32][64];
  __shared__ float Bs[32][64];
  const int tid = threadIdx.x;
  const int bm = blockIdx.y * 64;
  const int bn = blockIdx.x * 64;
  const int tx = tid & 15;
  const int ty = tid >> 4;
  const int lr = tid & 63;
  const int lq = tid >> 6;
  float acc[4][4] = {};
  for (int k0 = 0; k0 < K; k0 += 32) {
#pragma unroll
    for (int s = 0; s < 2; ++s) {
      const int q = lq + s * 4;
      const int gm = bm + lr;
      float4 va = make_float4(0.f, 0.f, 0.f, 0.f);
      if (gm < M) va = *(const float4*)(A + (size_t)gm * K + k0 + q * 4);
      As[q * 4 + 0][lr] = va.x; As[q * 4 + 1][lr] = va.y;
      As[q * 4 + 2][lr] = va.z; As[q * 4 + 3][lr] = va.w;
      const int gn = bn + lr;
      float4 vb = *(const float4*)(B + (size_t)gn * K + k0 + q * 4);
      Bs[q * 4 + 0][lr] = vb.x; Bs[q * 4 + 1][lr] = vb.y;
      Bs[q * 4 + 2][lr] = vb.z; Bs[q * 4 + 3][lr] = vb.w;
    }
    __syncthreads();
#pragma unroll
    for (int kk = 0; kk < 32; ++kk) {
      float a[4], b[4];
#pragma unroll
      for (int i2 = 0; i2 < 4; ++i2) { a[i2] = As[kk][ty * 4 + i2]; b[i2] = Bs[kk][tx * 4 + i2]; }
#pragma unroll
      for (int i2 = 0; i2 < 4; ++i2)
#pragma unroll
        for (int j2 = 0; j2 < 4; ++j2)
          acc[i2][j2] = fmaf(a[i2], b[j2], acc[i2][j2]);
    }
    __syncthreads();
  }
#pragma unroll
  for (int i2 = 0; i2 < 4; ++i2) {
    const int gm = bm + ty * 4 + i2;
    if (gm >= M) continue;
#pragma unroll
    for (int j2 = 0; j2 < 4; ++j2)
      C[(size_t)gm * N + bn + tx * 4 + j2] = acc[i2][j2];
  }
}

__global__ void to_bf16(const float* __restrict__ in, unsigned short* __restrict__ out, int n) {
  int i = blockIdx.x * 256 + threadIdx.x;
  if (i < n) out[i] = f2bf(in[i]);
}

// dst[(r*RANK+k)*D + d] = src[r*(D*RANK) + d*RANK + k]   (fp32, for A-side)
__global__ void expand_lora(const float* __restrict__ src, float* __restrict__ dst,
                            int R, int D) {
  int idx = blockIdx.x * blockDim.x + threadIdx.x;
  int total = R * RANK * D;
  if (idx >= total) return;
  int d = idx % D;
  int rk = idx / D;
  int k = rk % RANK;
  int r = rk / RANK;
  dst[idx] = src[(size_t)r * D * RANK + (size_t)d * RANK + k];
}

// bf16 variant (for B-side feeding MFMA)
__global__ void expand_lora_bf16(const float* __restrict__ src, unsigned short* __restrict__ dst,
                                 int R, int D) {
  int idx = blockIdx.x * blockDim.x + threadIdx.x;
  int total = R * RANK * D;
  if (idx >= total) return;
  int d = idx % D;
  int rk = idx / D;
  int k = rk % RANK;
  int r = rk / RANK;
  dst[idx] = f2bf(src[(size_t)r * D * RANK + (size_t)d * RANK + k]);
}

__global__ void matt1_kernel(const float* __restrict__ M1, const float* __restrict__ attR,
                             float* __restrict__ Matt1) {
  int idx = threadIdx.x;
  int h = idx & 3, rk = idx >> 2;
  float s = 0.f;
  for (int c = 0; c < HID; ++c) s = fmaf(M1[(size_t)rk * D2 + h * HID + c], attR[h * HID + c], s);
  Matt1[rk * 4 + h] = s;
}

__global__ void matt2_kernel(const float* __restrict__ M2, const float* __restrict__ attR,
                             float* __restrict__ Matt2) {
  int rk = threadIdx.x;
  float s = 0.f;
  for (int c = 0; c < OUTD; ++c) s = fmaf(M2[(size_t)rk * OUTD + c], attR[c], s);
  Matt2[rk] = s;
}

__global__ void rowdot(const float* __restrict__ Z, const float* __restrict__ attL,
                       const float* __restrict__ attR, float* __restrict__ al,
                       float* __restrict__ ar, int Nn, int H, int C) {
  int idx = blockIdx.x * blockDim.x + threadIdx.x;
  if (idx >= Nn * H) return;
  int h = idx % H, n = idx / H;
  const float* z = Z + (size_t)n * H * C + (size_t)h * C;
  const float* L = attL + (size_t)h * C;
  const float* R = attR + (size_t)h * C;
  float sl = 0.f, sr = 0.f;
  for (int c = 0; c < C; ++c) { float zv = z[c]; sl = fmaf(zv, L[c], sl); sr = fmaf(zv, R[c], sr); }
  al[idx] = sl;
  ar[idx] = sr;
}

// ---------------- CSR build over target node i ----------------
__global__ void hist_kernel(const int* __restrict__ ii, int* __restrict__ deg, int E) {
  int e = blockIdx.x * blockDim.x + threadIdx.x;
  if (e < E) atomicAdd(&deg[ii[e]], 1);
}

__global__ __launch_bounds__(1024) void exscan_kernel(const int* __restrict__ deg,
                                                      int* __restrict__ rowstart, int n) {
  __shared__ int s[1024];
  __shared__ int carry;
  int t = threadIdx.x;
  if (t == 0) carry = 0;
  __syncthreads();
  for (int base = 0; base < n; base += 1024) {
    int v = (base + t < n) ? deg[base + t] : 0;
    s[t] = v;
    __syncthreads();
    for (int o = 1; o < 1024; o <<= 1) {
      int x = (t >= o) ? s[t - o] : 0;
      __syncthreads();
      s[t] += x;
      __syncthreads();
    }
    if (base + t < n) rowstart[base + t] = carry + s[t] - v;
    if (t == 1023) s[0] = carry + s[1023];
    __syncthreads();
    if (t == 0) carry = s[0];
    __syncthreads();
  }
  if (t == 0) rowstart[n] = carry;
}

__global__ void scatter_kernel(const int* __restrict__ ii, const int* __restrict__ rowstart,
                               int* __restrict__ cursor, int* __restrict__ eid, int E) {
  int e = blockIdx.x * blockDim.x + threadIdx.x;
  if (e >= E) return;
  int i = ii[e];
  int p = atomicAdd(&cursor[i], 1);
  eid[rowstart[i] + p] = e;
}

// ---------------- Layer-1 edge logits ----------------
__global__ void edge_alpha1(const int* __restrict__ ji, const int* __restrict__ ii,
                            const int* __restrict__ et, const float* __restrict__ P1,
                            const float* __restrict__ al1, const float* __restrict__ ar1,
                            const float* __restrict__ relb1, const float* __restrict__ Matt1,
                            float* __restrict__ ex1, int E) {
  int e = blockIdx.x * blockDim.x + threadIdx.x;
  if (e >= E) return;
  int j = ji[e], i = ii[e], rt = et[e];
  float low[RANK];
#pragma unroll
  for (int k = 0; k < RANK; ++k) low[k] = P1[(size_t)j * 64 + rt * RANK + k];
#pragma unroll
  for (int h = 0; h < HEADS; ++h) {
    float a = al1[i * 4 + h] + ar1[j * 4 + h] + relb1[rt * 4 + h];
#pragma unroll
    for (int k = 0; k < RANK; ++k) a = fmaf(low[k], Matt1[(rt * RANK + k) * 4 + h], a);
    a = (a > 0.f) ? a : NEG_SLOPE * a;
    ex1[(size_t)e * 4 + h] = expf(a);
  }
}

// ---------------- Layer-1 CSR gather: softmax + aggregate + bias + ELU -> bf16 h1 ----------------
__global__ __launch_bounds__(256) void node_agg1(const int* __restrict__ ji,
    const int* __restrict__ et, const int* __restrict__ rowstart, const int* __restrict__ eid,
    const float* __restrict__ P1, const float* __restrict__ M1, const float* __restrict__ ex1,
    const float* __restrict__ z1, const float* __restrict__ bias1,
    unsigned short* __restrict__ h1out, int Nn) {
  int i = blockIdx.x;
  int t = threadIdx.x;
  int s0 = rowstart[i], s1 = rowstart[i + 1];
  int deg = s1 - s0;
  __shared__ float s_den[NRELS * HEADS];
  if (t < NRELS * HEADS) s_den[t] = 0.f;
  __syncthreads();
  for (int p = t; p < deg * HEADS; p += 256) {
    int e = eid[s0 + (p >> 2)];
    int h = p & 3;
    atomicAdd(&s_den[et[e] * HEADS + h], ex1[(size_t)e * 4 + h]);
  }
  __syncthreads();
  const int c0 = t, c1 = t + 256;
  const int ha = c0 >> 7, hb = c1 >> 7;
  float acc0 = 0.f, acc1 = 0.f;
  for (int p = 0; p < deg; ++p) {
    int e = eid[s0 + p];
    int j = ji[e], rt = et[e];
    float w0 = ex1[(size_t)e * 4 + ha] / s_den[rt * 4 + ha];
    float w1 = ex1[(size_t)e * 4 + hb] / s_den[rt * 4 + hb];
    float low[RANK];
#pragma unroll
    for (int k = 0; k < RANK; ++k) low[k] = P1[(size_t)j * 64 + rt * 8 + k];
    float v0 = z1[(size_t)j * D2 + c0];
    float v1 = z1[(size_t)j * D2 + c1];
#pragma unroll
    for (int k = 0; k < RANK; ++k) {
      const float* m = M1 + (size_t)(rt * 8 + k) * D2;
      v0 = fmaf(low[k], m[c0], v0);
      v1 = fmaf(low[k], m[c1], v1);
    }
    acc0 = fmaf(w0, v0, acc0);
    acc1 = fmaf(w1, v1, acc1);
  }
  float r0 = acc0 + bias1[c0];
  float r1 = acc1 + bias1[c1];
  h1out[(size_t)i * D2 + c0] = f2bf(r0 > 0.f ? r0 : expm1f(r0));
  h1out[(size_t)i * D2 + c1] = f2bf(r1 > 0.f ? r1 : expm1f(r1));
}

// ---------------- Layer-2 edge logits ----------------
__global__ void edge_alpha2(const int* __restrict__ ji, const int* __restrict__ ii,
                            const int* __restrict__ et, const float* __restrict__ P2,
                            const float* __restrict__ al2, const float* __restrict__ ar2,
                            const float* __restrict__ relb2, const float* __restrict__ Matt2,
                            float* __restrict__ ex2, int E) {
  int e = blockIdx.x * blockDim.x + threadIdx.x;
  if (e >= E) return;
  int j = ji[e], i = ii[e], rt = et[e];
  float a = al2[i] + ar2[j] + relb2[rt];
#pragma unroll
  for (int k = 0; k < RANK; ++k)
    a = fmaf(P2[(size_t)j * 64 + rt * RANK + k], Matt2[rt * RANK + k], a);
  a = (a > 0.f) ? a : NEG_SLOPE * a;
  ex2[e] = expf(a);
}

// ---------------- Layer-2 CSR gather + residual + bias + LayerNorm -> out ----------------
__global__ __launch_bounds__(256) void node_agg2(const int* __restrict__ ji,
    const int* __restrict__ et, const int* __restrict__ rowstart, const int* __restrict__ eid,
    const float* __restrict__ P2, const float* __restrict__ M2, const float* __restrict__ ex2,
    const float* __restrict__ z2, const float* __restrict__ res,
    const float* __restrict__ bias2, const float* __restrict__ res_b,
    const float* __restrict__ ln_g, const float* __restrict__ ln_b,
    float* __restrict__ y, int Nn) {
  int i = blockIdx.x;
  int t = threadIdx.x;
  int s0 = rowstart[i], s1 = rowstart[i + 1];
  int deg = s1 - s0;
  __shared__ float s_den[NRELS];
  __shared__ float red[256];
  if (t < NRELS) s_den[t] = 0.f;
  __syncthreads();
  for (int p = t; p < deg; p += 256) {
    int e = eid[s0 + p];
    atomicAdd(&s_den[et[e]], ex2[e]);
  }
  __syncthreads();
  float acc = 0.f;
  for (int p = 0; p < deg; ++p) {
    int e = eid[s0 + p];
    int j = ji[e], rt = et[e];
    float wgt = ex2[e] / s_den[rt];
    float low[RANK];
#pragma unroll
    for (int k = 0; k < RANK; ++k) low[k] = P2[(size_t)j * 64 + rt * 8 + k];
    float v = z2[(size_t)j * OUTD + t];
#pragma unroll
    for (int k = 0; k < RANK; ++k)
      v = fmaf(low[k], M2[(size_t)(rt * 8 + k) * OUTD + t], v);
    acc = fmaf(wgt, v, acc);
  }
  float v = acc + res[(size_t)i * OUTD + t] + bias2[t] + res_b[t];
  red[t] = v;
  __syncthreads();
  for (int s = 128; s > 0; s >>= 1) { if (t < s) red[t] += red[t + s]; __syncthreads(); }
  float mu = red[0] / OUTD;
  __syncthreads();
  float d = v - mu;
  red[t] = d * d;
  __syncthreads();
  for (int s = 128; s > 0; s >>= 1) { if (t < s) red[t] += red[t + s]; __syncthreads(); }
  float var = red[0] / OUTD;
  y[(size_t)i * OUTD + t] = d * rsqrtf(var + LN_EPS) * ln_g[t] + ln_b[t];
}

extern "C" void kernel_launch(void* const* d_in, const int* in_sizes, int n_in,
                              void* d_out, int out_size, void* d_ws, size_t ws_size,
                              hipStream_t stream) {
  const float* x0     = (const float*)d_in[0];
  const float* A1     = (const float*)d_in[1];
  const float* B1     = (const float*)d_in[2];
  const float* W1     = (const float*)d_in[3];
  const float* attL1  = (const float*)d_in[4];
  const float* attR1  = (const float*)d_in[5];
  const float* relb1  = (const float*)d_in[6];
  const float* bias1  = (const float*)d_in[7];
  const float* A2     = (const float*)d_in[8];
  const float* B2     = (const float*)d_in[9];
  const float* W2     = (const float*)d_in[10];
  const float* attL2  = (const float*)d_in[11];
  const float* attR2  = (const float*)d_in[12];
  const float* relb2  = (const float*)d_in[13];
  const float* bias2  = (const float*)d_in[14];
  const float* res_W  = (const float*)d_in[15];
  const float* res_b  = (const float*)d_in[16];
  const float* ln_g   = (const float*)d_in[17];
  const float* ln_b   = (const float*)d_in[18];
  const int*   eidx   = (const int*)d_in[19];
  const int*   etype  = (const int*)d_in[20];
  float* out = (float*)d_out;

  const int Nn = in_sizes[0] / EMB;     // 30000
  const int E  = in_sizes[20];          // 150000
  const int* ji = eidx;
  const int* ii = eidx + E;

  // ---- workspace carve-up (float units; bf16 arrays placed on 4-float boundaries) ----
  float* w = (float*)d_ws;
  size_t off = 0;
  float* z1    = w + off; off += (size_t)Nn * D2;
  float* z2    = w + off; off += (size_t)Nn * OUTD;
  float* o2    = w + off; off += (size_t)Nn * OUTD;
  float* P1    = w + off; off += (size_t)Nn * 64;
  float* P2    = w + off; off += (size_t)Nn * 64;
  float* M1    = w + off; off += 64 * D2;
  float* M2    = w + off; off += 64 * OUTD;
  float* Amat1 = w + off; off += 64 * EMB;
  float* Amat2 = w + off; off += 64 * D2;
  float* Matt1 = w + off; off += 64 * 4;
  float* Matt2 = w + off; off += 64;
  float* al1   = w + off; off += (size_t)Nn * 4;
  float* ar1   = w + off; off += (size_t)Nn * 4;
  float* al2   = w + off; off += (size_t)Nn;
  float* ar2   = w + off; off += (size_t)Nn;
  float* ex1   = w + off; off += (size_t)E * 4;
  float* ex2   = w + off; off += (size_t)E;
  unsigned short* x0b    = (unsigned short*)(w + off); off += (size_t)Nn * EMB / 2;
  unsigned short* h1b    = (unsigned short*)(w + off); off += (size_t)Nn * D2 / 2;
  unsigned short* W1b    = (unsigned short*)(w + off); off += (size_t)D2 * EMB / 2;
  unsigned short* W2b    = (unsigned short*)(w + off); off += (size_t)OUTD * D2 / 2;
  unsigned short* resWb  = (unsigned short*)(w + off); off += (size_t)OUTD * EMB / 2;
  unsigned short* Bmat1b = (unsigned short*)(w + off); off += (size_t)64 * EMB / 2;
  unsigned short* Bmat2b = (unsigned short*)(w + off); off += (size_t)64 * D2 / 2;
  int* ideg     = (int*)(w + off); off += (size_t)Nn;
  int* rowstart = (int*)(w + off); off += (size_t)Nn + 1;
  int* cursor   = (int*)(w + off); off += (size_t)Nn;
  int* eid      = (int*)(w + off); off += (size_t)E;
  (void)ws_size; (void)n_in; (void)out_size;

  const int MT64 = (Nn + 63) / 64;   // 469 m-tiles

  // 0) CSR build
  (void)hipMemsetAsync(ideg, 0, (size_t)Nn * sizeof(int), stream);
  (void)hipMemsetAsync(cursor, 0, (size_t)Nn * sizeof(int), stream);
  hist_kernel<<<(E + 255) / 256, 256, 0, stream>>>(ii, ideg, E);
  exscan_kernel<<<1, 1024, 0, stream>>>(ideg, rowstart, Nn);
  scatter_kernel<<<(E + 255) / 256, 256, 0, stream>>>(ii, rowstart, cursor, eid, E);

  // 1) LoRA re-layouts
  expand_lora<<<(64 * EMB + 255) / 256, 256, 0, stream>>>(A1, Amat1, NRELS, EMB);
  expand_lora<<<(64 * D2 + 255) / 256, 256, 0, stream>>>(A2, Amat2, NRELS, D2);
  expand_lora_bf16<<<(64 * EMB + 255) / 256, 256, 0, stream>>>(B1, Bmat1b, NRELS, EMB);
  expand_lora_bf16<<<(64 * D2 + 255) / 256, 256, 0, stream>>>(B2, Bmat2b, NRELS, D2);

  // 2) bf16 conversions
  to_bf16<<<(Nn * EMB + 255) / 256, 256, 0, stream>>>(x0, x0b, Nn * EMB);
  to_bf16<<<(D2 * EMB + 255) / 256, 256, 0, stream>>>(W1, W1b, D2 * EMB);
  to_bf16<<<(OUTD * D2 + 255) / 256, 256, 0, stream>>>(W2, W2b, OUTD * D2);
  to_bf16<<<(OUTD * EMB + 255) / 256, 256, 0, stream>>>(res_W, resWb, OUTD * EMB);

  // 3) M1 = Amat1 @ W1^T ; M2 = Amat2 @ W2^T  (fp32, tiny)
  gemm_abt<<<dim3(D2 / 64, 1), 256, 0, stream>>>(Amat1, W1, M1, 64, D2, EMB);
  gemm_abt<<<dim3(OUTD / 64, 1), 256, 0, stream>>>(Amat2, W2, M2, 64, OUTD, D2);
  matt1_kernel<<<1, 256, 0, stream>>>(M1, attR1, Matt1);
  matt2_kernel<<<1, 64, 0, stream>>>(M2, attR2, Matt2);

  // 4) Layer-1 node GEMMs (tiled bf16 MFMA)
  gemm_bf16t<<<dim3(MT64, D2 / 64), 256, 0, stream>>>(x0b, W1b, z1, Nn, D2, EMB);
  gemm_bf16t<<<dim3(MT64, 1), 256, 0, stream>>>(x0b, Bmat1b, P1, Nn, 64, EMB);

  // 5) attention dots
  rowdot<<<(Nn * 4 + 255) / 256, 256, 0, stream>>>(z1, attL1, attR1, al1, ar1, Nn, HEADS, HID);

  // 6) Layer-1 edge logits + CSR gather
  edge_alpha1<<<(E + 255) / 256, 256, 0, stream>>>(ji, ii, etype, P1, al1, ar1, relb1, Matt1,
                                                   ex1, E);
  node_agg1<<<Nn, 256, 0, stream>>>(ji, etype, rowstart, eid, P1, M1, ex1, z1, bias1, h1b, Nn);

  // 7) Layer-2 node GEMMs + residual (tiled bf16 MFMA)
  gemm_bf16t<<<dim3(MT64, OUTD / 64), 256, 0, stream>>>(h1b, W2b, z2, Nn, OUTD, D2);
  gemm_bf16t<<<dim3(MT64, 1), 256, 0, stream>>>(h1b, Bmat2b, P2, Nn, 64, D2);
  gemm_bf16t<<<dim3(MT64, OUTD / 64), 256, 0, stream>>>(x0b, resWb, o2, Nn, OUTD, EMB);

  // 8) Layer-2 attention dots
  rowdot<<<(Nn + 255) / 256, 256, 0, stream>>>(z2, attL2, attR2, al2, ar2, Nn, 1, OUTD);

  // 9) Layer-2 edge logits + CSR gather (fused residual/bias/LN)
  edge_alpha2<<<(E + 255) / 256, 256, 0, stream>>>(ji, ii, etype, P2, al2, ar2, relb2, Matt2,
                                                   ex2, E);
  node_agg2<<<Nn, 256, 0, stream>>>(ji, etype, rowstart, eid, P2, M2, ex2, z2, o2,
                                    bias2, res_b, ln_g, ln_b, out, Nn);
}

// Round 7
// 681.939 us; speedup vs baseline: 1.5002x; 1.0249x over previous
//
#include <hip/hip_runtime.h>
#include <cstddef>

#define NRELS 8
#define EMB 128
#define HID 128
#define OUTD 256
#define HEADS 4
#define RANK 8
#define D2 512            // HEADS*HID, conv2 input dim
#define NEG_SLOPE 0.2f
#define LN_EPS 1e-5f

typedef short bf16x8 __attribute__((ext_vector_type(8)));   // 8 bf16 in 4 VGPRs
typedef float f32x4 __attribute__((ext_vector_type(4)));

__device__ __forceinline__ unsigned short f2bf(float f) {   // RNE
  union { float f; unsigned u; } v; v.f = f;
  unsigned u = v.u;
  return (unsigned short)((u + 0x7fffu + ((u >> 16) & 1u)) >> 16);
}

// ---------------- Big-tile bf16 MFMA GEMM: C[M,N] = A[M,K] @ B[N,K]^T ----------------
// 128x128 block tile, BK=32, 256 threads = 4 waves; wave (wm,wn) owns a 64x64 quadrant
// via 4x4 grid of 16x16x32 MFMA accumulators (64 MFMAs per block per k-step).
// LDS rows padded to 36 bf16 (72 B = 18 banks; stride-18 row starts are distinct mod 32
// => <=2-way conflicts, free per m136). K%32==0, N%128==0; M guarded.
__global__ __launch_bounds__(256) void gemm_big(const unsigned short* __restrict__ A,
    const unsigned short* __restrict__ B, float* __restrict__ C, int M, int N, int K) {
  __shared__ unsigned short As[128][36];
  __shared__ unsigned short Bs[128][36];
  const int tid = threadIdx.x;
  const int wave = tid >> 6;
  const int lane = tid & 63;
  const int wm = wave & 1;
  const int wn = wave >> 1;
  const int r16 = lane & 15;
  const int quad = lane >> 4;
  const int bm = blockIdx.x * 128;
  const int bn = blockIdx.y * 128;
  // staging: thread t loads 8 bf16 (16 B); 4 threads/row cover 32 cols; 64 rows/round
  const int srow = tid >> 2;         // 0..63
  const int scol = (tid & 3) * 8;    // 0,8,16,24
  int ar0 = bm + srow;      if (ar0 >= M) ar0 = M - 1;   // clamp; C-store guarded
  int ar1 = bm + 64 + srow; if (ar1 >= M) ar1 = M - 1;
  const unsigned short* Ag0 = A + (size_t)ar0 * K + scol;
  const unsigned short* Ag1 = A + (size_t)ar1 * K + scol;
  const unsigned short* Bg0 = B + (size_t)(bn + srow) * K + scol;
  const unsigned short* Bg1 = B + (size_t)(bn + 64 + srow) * K + scol;
  f32x4 acc[4][4] = {};
  for (int k0 = 0; k0 < K; k0 += 32) {
    bf16x8 a0 = *(const bf16x8*)(Ag0 + k0);
    bf16x8 a1 = *(const bf16x8*)(Ag1 + k0);
    bf16x8 b0 = *(const bf16x8*)(Bg0 + k0);
    bf16x8 b1 = *(const bf16x8*)(Bg1 + k0);
    __syncthreads();                 // protect previous iteration's reads
    *(bf16x8*)(&As[srow][scol]) = a0;
    *(bf16x8*)(&As[64 + srow][scol]) = a1;
    *(bf16x8*)(&Bs[srow][scol]) = b0;
    *(bf16x8*)(&Bs[64 + srow][scol]) = b1;
    __syncthreads();
    bf16x8 af[4], bfr[4];
#pragma unroll
    for (int mi = 0; mi < 4; ++mi)
      af[mi] = *(const bf16x8*)(&As[wm * 64 + mi * 16 + r16][quad * 8]);
#pragma unroll
    for (int ni = 0; ni < 4; ++ni)
      bfr[ni] = *(const bf16x8*)(&Bs[wn * 64 + ni * 16 + r16][quad * 8]);
#pragma unroll
    for (int mi = 0; mi < 4; ++mi)
#pragma unroll
      for (int ni = 0; ni < 4; ++ni)
        acc[mi][ni] = __builtin_amdgcn_mfma_f32_16x16x32_bf16(af[mi], bfr[ni], acc[mi][ni], 0, 0, 0);
  }
  // C/D layout: col = lane&15, row = quad*4 + reg   [m89-verified]
#pragma unroll
  for (int mi = 0; mi < 4; ++mi)
#pragma unroll
    for (int ni = 0; ni < 4; ++ni)
#pragma unroll
      for (int r = 0; r < 4; ++r) {
        int row = bm + wm * 64 + mi * 16 + quad * 4 + r;
        if (row < M)
          C[(size_t)row * N + bn + wn * 64 + ni * 16 + r16] = acc[mi][ni][r];
      }
}

// ---------------- 64x64 bf16 MFMA GEMM (for N=64 P-projections) ----------------
__global__ __launch_bounds__(256) void gemm_bf16t(const unsigned short* __restrict__ A,
    const unsigned short* __restrict__ B, float* __restrict__ C, int M, int N, int K) {
  __shared__ unsigned short As[64][40];
  __shared__ unsigned short Bs[64][40];
  const int tid = threadIdx.x;
  const int wave = tid >> 6;
  const int lane = tid & 63;
  const int wm = wave & 1;
  const int wn = wave >> 1;
  const int r16 = lane & 15;
  const int quad = lane >> 4;
  const int bm = blockIdx.x * 64;
  const int bn = blockIdx.y * 64;
  const int srow = tid >> 2;
  const int schunk = tid & 3;
  int arow = bm + srow; if (arow >= M) arow = M - 1;
  const unsigned short* Ag = A + (size_t)arow * K + schunk * 8;
  const unsigned short* Bg = B + (size_t)(bn + srow) * K + schunk * 8;
  f32x4 acc[2][2] = {};
  for (int k0 = 0; k0 < K; k0 += 32) {
    bf16x8 av = *(const bf16x8*)(Ag + k0);
    bf16x8 bv = *(const bf16x8*)(Bg + k0);
    __syncthreads();
    *(bf16x8*)(&As[srow][schunk * 8]) = av;
    *(bf16x8*)(&Bs[srow][schunk * 8]) = bv;
    __syncthreads();
    bf16x8 af0 = *(const bf16x8*)(&As[wm * 32 + r16][quad * 8]);
    bf16x8 af1 = *(const bf16x8*)(&As[wm * 32 + 16 + r16][quad * 8]);
    bf16x8 bf0 = *(const bf16x8*)(&Bs[wn * 32 + r16][quad * 8]);
    bf16x8 bf1 = *(const bf16x8*)(&Bs[wn * 32 + 16 + r16][quad * 8]);
    acc[0][0] = __builtin_amdgcn_mfma_f32_16x16x32_bf16(af0, bf0, acc[0][0], 0, 0, 0);
    acc[0][1] = __builtin_amdgcn_mfma_f32_16x16x32_bf16(af0, bf1, acc[0][1], 0, 0, 0);
    acc[1][0] = __builtin_amdgcn_mfma_f32_16x16x32_bf16(af1, bf0, acc[1][0], 0, 0, 0);
    acc[1][1] = __builtin_amdgcn_mfma_f32_16x16x32_bf16(af1, bf1, acc[1][1], 0, 0, 0);
  }
#pragma unroll
  for (int mi = 0; mi < 2; ++mi)
#pragma unroll
    for (int ni = 0; ni < 2; ++ni)
#pragma unroll
      for (int r = 0; r < 4; ++r) {
        int row = bm + wm * 32 + mi * 16 + quad * 4 + r;
        if (row < M)
          C[(size_t)row * N + bn + wn * 32 + ni * 16 + r16] = acc[mi][ni][r];
      }
}

// ---------------- fp32 tiled GEMM (only for tiny M1/M2 precompute) ----------------
__global__ __launch_bounds__(256) void gemm_abt(const float* __restrict__ A,
    const float* __restrict__ B, float* __restrict__ C, int M, int N, int K) {
  __shared__ float As[32][64];
  __shared__ float Bs[32][64];
  const int tid = threadIdx.x;
  const int bm = blockIdx.y * 64;
  const int bn = blockIdx.x * 64;
  const int tx = tid & 15;
  const int ty = tid >> 4;
  const int lr = tid & 63;
  const int lq = tid >> 6;
  float acc[4][4] = {};
  for (int k0 = 0; k0 < K; k0 += 32) {
#pragma unroll
    for (int s = 0; s < 2; ++s) {
      const int q = lq + s * 4;
      const int gm = bm + lr;
      float4 va = make_float4(0.f, 0.f, 0.f, 0.f);
      if (gm < M) va = *(const float4*)(A + (size_t)gm * K + k0 + q * 4);
      As[q * 4 + 0][lr] = va.x; As[q * 4 + 1][lr] = va.y;
      As[q * 4 + 2][lr] = va.z; As[q * 4 + 3][lr] = va.w;
      const int gn = bn + lr;
      float4 vb = *(const float4*)(B + (size_t)gn * K + k0 + q * 4);
      Bs[q * 4 + 0][lr] = vb.x; Bs[q * 4 + 1][lr] = vb.y;
      Bs[q * 4 + 2][lr] = vb.z; Bs[q * 4 + 3][lr] = vb.w;
    }
    __syncthreads();
#pragma unroll
    for (int kk = 0; kk < 32; ++kk) {
      float a[4], b[4];
#pragma unroll
      for (int i2 = 0; i2 < 4; ++i2) { a[i2] = As[kk][ty * 4 + i2]; b[i2] = Bs[kk][tx * 4 + i2]; }
#pragma unroll
      for (int i2 = 0; i2 < 4; ++i2)
#pragma unroll
        for (int j2 = 0; j2 < 4; ++j2)
          acc[i2][j2] = fmaf(a[i2], b[j2], acc[i2][j2]);
    }
    __syncthreads();
  }
#pragma unroll
  for (int i2 = 0; i2 < 4; ++i2) {
    const int gm = bm + ty * 4 + i2;
    if (gm >= M) continue;
#pragma unroll
    for (int j2 = 0; j2 < 4; ++j2)
      C[(size_t)gm * N + bn + tx * 4 + j2] = acc[i2][j2];
  }
}

__global__ void to_bf16(const float* __restrict__ in, unsigned short* __restrict__ out, int n) {
  int i = blockIdx.x * 256 + threadIdx.x;
  if (i < n) out[i] = f2bf(in[i]);
}

// dst[(r*RANK+k)*D + d] = src[r*(D*RANK) + d*RANK + k]   (fp32, for A-side)
__global__ void expand_lora(const float* __restrict__ src, float* __restrict__ dst,
                            int R, int D) {
  int idx = blockIdx.x * blockDim.x + threadIdx.x;
  int total = R * RANK * D;
  if (idx >= total) return;
  int d = idx % D;
  int rk = idx / D;
  int k = rk % RANK;
  int r = rk / RANK;
  dst[idx] = src[(size_t)r * D * RANK + (size_t)d * RANK + k];
}

// bf16 variant (for B-side feeding MFMA)
__global__ void expand_lora_bf16(const float* __restrict__ src, unsigned short* __restrict__ dst,
                                 int R, int D) {
  int idx = blockIdx.x * blockDim.x + threadIdx.x;
  int total = R * RANK * D;
  if (idx >= total) return;
  int d = idx % D;
  int rk = idx / D;
  int k = rk % RANK;
  int r = rk / RANK;
  dst[idx] = f2bf(src[(size_t)r * D * RANK + (size_t)d * RANK + k]);
}

__global__ void matt1_kernel(const float* __restrict__ M1, const float* __restrict__ attR,
                             float* __restrict__ Matt1) {
  int idx = threadIdx.x;
  int h = idx & 3, rk = idx >> 2;
  float s = 0.f;
  for (int c = 0; c < HID; ++c) s = fmaf(M1[(size_t)rk * D2 + h * HID + c], attR[h * HID + c], s);
  Matt1[rk * 4 + h] = s;
}

__global__ void matt2_kernel(const float* __restrict__ M2, const float* __restrict__ attR,
                             float* __restrict__ Matt2) {
  int rk = threadIdx.x;
  float s = 0.f;
  for (int c = 0; c < OUTD; ++c) s = fmaf(M2[(size_t)rk * OUTD + c], attR[c], s);
  Matt2[rk] = s;
}

__global__ void rowdot(const float* __restrict__ Z, const float* __restrict__ attL,
                       const float* __restrict__ attR, float* __restrict__ al,
                       float* __restrict__ ar, int Nn, int H, int C) {
  int idx = blockIdx.x * blockDim.x + threadIdx.x;
  if (idx >= Nn * H) return;
  int h = idx % H, n = idx / H;
  const float* z = Z + (size_t)n * H * C + (size_t)h * C;
  const float* L = attL + (size_t)h * C;
  const float* R = attR + (size_t)h * C;
  float sl = 0.f, sr = 0.f;
  for (int c = 0; c < C; ++c) { float zv = z[c]; sl = fmaf(zv, L[c], sl); sr = fmaf(zv, R[c], sr); }
  al[idx] = sl;
  ar[idx] = sr;
}

// ---------------- CSR build over target node i ----------------
__global__ void hist_kernel(const int* __restrict__ ii, int* __restrict__ deg, int E) {
  int e = blockIdx.x * blockDim.x + threadIdx.x;
  if (e < E) atomicAdd(&deg[ii[e]], 1);
}

__global__ __launch_bounds__(1024) void exscan_kernel(const int* __restrict__ deg,
                                                      int* __restrict__ rowstart, int n) {
  __shared__ int s[1024];
  __shared__ int carry;
  int t = threadIdx.x;
  if (t == 0) carry = 0;
  __syncthreads();
  for (int base = 0; base < n; base += 1024) {
    int v = (base + t < n) ? deg[base + t] : 0;
    s[t] = v;
    __syncthreads();
    for (int o = 1; o < 1024; o <<= 1) {
      int x = (t >= o) ? s[t - o] : 0;
      __syncthreads();
      s[t] += x;
      __syncthreads();
    }
    if (base + t < n) rowstart[base + t] = carry + s[t] - v;
    if (t == 1023) s[0] = carry + s[1023];
    __syncthreads();
    if (t == 0) carry = s[0];
    __syncthreads();
  }
  if (t == 0) rowstart[n] = carry;
}

__global__ void scatter_kernel(const int* __restrict__ ii, const int* __restrict__ rowstart,
                               int* __restrict__ cursor, int* __restrict__ eid, int E) {
  int e = blockIdx.x * blockDim.x + threadIdx.x;
  if (e >= E) return;
  int i = ii[e];
  int p = atomicAdd(&cursor[i], 1);
  eid[rowstart[i] + p] = e;
}

// ---------------- Layer-1 edge logits ----------------
__global__ void edge_alpha1(const int* __restrict__ ji, const int* __restrict__ ii,
                            const int* __restrict__ et, const float* __restrict__ P1,
                            const float* __restrict__ al1, const float* __restrict__ ar1,
                            const float* __restrict__ relb1, const float* __restrict__ Matt1,
                            float* __restrict__ ex1, int E) {
  int e = blockIdx.x * blockDim.x + threadIdx.x;
  if (e >= E) return;
  int j = ji[e], i = ii[e], rt = et[e];
  float low[RANK];
#pragma unroll
  for (int k = 0; k < RANK; ++k) low[k] = P1[(size_t)j * 64 + rt * RANK + k];
#pragma unroll
  for (int h = 0; h < HEADS; ++h) {
    float a = al1[i * 4 + h] + ar1[j * 4 + h] + relb1[rt * 4 + h];
#pragma unroll
    for (int k = 0; k < RANK; ++k) a = fmaf(low[k], Matt1[(rt * RANK + k) * 4 + h], a);
    a = (a > 0.f) ? a : NEG_SLOPE * a;
    ex1[(size_t)e * 4 + h] = expf(a);
  }
}

// ---------------- Layer-1 CSR gather: softmax + aggregate + bias + ELU -> bf16 h1 ----------------
__global__ __launch_bounds__(256) void node_agg1(const int* __restrict__ ji,
    const int* __restrict__ et, const int* __restrict__ rowstart, const int* __restrict__ eid,
    const float* __restrict__ P1, const float* __restrict__ M1, const float* __restrict__ ex1,
    const float* __restrict__ z1, const float* __restrict__ bias1,
    unsigned short* __restrict__ h1out, int Nn) {
  int i = blockIdx.x;
  int t = threadIdx.x;
  int s0 = rowstart[i], s1 = rowstart[i + 1];
  int deg = s1 - s0;
  __shared__ float s_den[NRELS * HEADS];
  if (t < NRELS * HEADS) s_den[t] = 0.f;
  __syncthreads();
  for (int p = t; p < deg * HEADS; p += 256) {
    int e = eid[s0 + (p >> 2)];
    int h = p & 3;
    atomicAdd(&s_den[et[e] * HEADS + h], ex1[(size_t)e * 4 + h]);
  }
  __syncthreads();
  const int c0 = t, c1 = t + 256;
  const int ha = c0 >> 7, hb = c1 >> 7;
  float acc0 = 0.f, acc1 = 0.f;
  for (int p = 0; p < deg; ++p) {
    int e = eid[s0 + p];
    int j = ji[e], rt = et[e];
    float w0 = ex1[(size_t)e * 4 + ha] / s_den[rt * 4 + ha];
    float w1 = ex1[(size_t)e * 4 + hb] / s_den[rt * 4 + hb];
    float low[RANK];
#pragma unroll
    for (int k = 0; k < RANK; ++k) low[k] = P1[(size_t)j * 64 + rt * 8 + k];
    float v0 = z1[(size_t)j * D2 + c0];
    float v1 = z1[(size_t)j * D2 + c1];
#pragma unroll
    for (int k = 0; k < RANK; ++k) {
      const float* m = M1 + (size_t)(rt * 8 + k) * D2;
      v0 = fmaf(low[k], m[c0], v0);
      v1 = fmaf(low[k], m[c1], v1);
    }
    acc0 = fmaf(w0, v0, acc0);
    acc1 = fmaf(w1, v1, acc1);
  }
  float r0 = acc0 + bias1[c0];
  float r1 = acc1 + bias1[c1];
  h1out[(size_t)i * D2 + c0] = f2bf(r0 > 0.f ? r0 : expm1f(r0));
  h1out[(size_t)i * D2 + c1] = f2bf(r1 > 0.f ? r1 : expm1f(r1));
}

// ---------------- Layer-2 edge logits ----------------
__global__ void edge_alpha2(const int* __restrict__ ji, const int* __restrict__ ii,
                            const int* __restrict__ et, const float* __restrict__ P2,
                            const float* __restrict__ al2, const float* __restrict__ ar2,
                            const float* __restrict__ relb2, const float* __restrict__ Matt2,
                            float* __restrict__ ex2, int E) {
  int e = blockIdx.x * blockDim.x + threadIdx.x;
  if (e >= E) return;
  int j = ji[e], i = ii[e], rt = et[e];
  float a = al2[i] + ar2[j] + relb2[rt];
#pragma unroll
  for (int k = 0; k < RANK; ++k)
    a = fmaf(P2[(size_t)j * 64 + rt * RANK + k], Matt2[rt * RANK + k], a);
  a = (a > 0.f) ? a : NEG_SLOPE * a;
  ex2[e] = expf(a);
}

// ---------------- Layer-2 CSR gather + residual + bias + LayerNorm -> out ----------------
__global__ __launch_bounds__(256) void node_agg2(const int* __restrict__ ji,
    const int* __restrict__ et, const int* __restrict__ rowstart, const int* __restrict__ eid,
    const float* __restrict__ P2, const float* __restrict__ M2, const float* __restrict__ ex2,
    const float* __restrict__ z2, const float* __restrict__ res,
    const float* __restrict__ bias2, const float* __restrict__ res_b,
    const float* __restrict__ ln_g, const float* __restrict__ ln_b,
    float* __restrict__ y, int Nn) {
  int i = blockIdx.x;
  int t = threadIdx.x;
  int s0 = rowstart[i], s1 = rowstart[i + 1];
  int deg = s1 - s0;
  __shared__ float s_den[NRELS];
  __shared__ float red[256];
  if (t < NRELS) s_den[t] = 0.f;
  __syncthreads();
  for (int p = t; p < deg; p += 256) {
    int e = eid[s0 + p];
    atomicAdd(&s_den[et[e]], ex2[e]);
  }
  __syncthreads();
  float acc = 0.f;
  for (int p = 0; p < deg; ++p) {
    int e = eid[s0 + p];
    int j = ji[e], rt = et[e];
    float wgt = ex2[e] / s_den[rt];
    float low[RANK];
#pragma unroll
    for (int k = 0; k < RANK; ++k) low[k] = P2[(size_t)j * 64 + rt * 8 + k];
    float v = z2[(size_t)j * OUTD + t];
#pragma unroll
    for (int k = 0; k < RANK; ++k)
      v = fmaf(low[k], M2[(size_t)(rt * 8 + k) * OUTD + t], v);
    acc = fmaf(wgt, v, acc);
  }
  float v = acc + res[(size_t)i * OUTD + t] + bias2[t] + res_b[t];
  red[t] = v;
  __syncthreads();
  for (int s = 128; s > 0; s >>= 1) { if (t < s) red[t] += red[t + s]; __syncthreads(); }
  float mu = red[0] / OUTD;
  __syncthreads();
  float d = v - mu;
  red[t] = d * d;
  __syncthreads();
  for (int s = 128; s > 0; s >>= 1) { if (t < s) red[t] += red[t + s]; __syncthreads(); }
  float var = red[0] / OUTD;
  y[(size_t)i * OUTD + t] = d * rsqrtf(var + LN_EPS) * ln_g[t] + ln_b[t];
}

extern "C" void kernel_launch(void* const* d_in, const int* in_sizes, int n_in,
                              void* d_out, int out_size, void* d_ws, size_t ws_size,
                              hipStream_t stream) {
  const float* x0     = (const float*)d_in[0];
  const float* A1     = (const float*)d_in[1];
  const float* B1     = (const float*)d_in[2];
  const float* W1     = (const float*)d_in[3];
  const float* attL1  = (const float*)d_in[4];
  const float* attR1  = (const float*)d_in[5];
  const float* relb1  = (const float*)d_in[6];
  const float* bias1  = (const float*)d_in[7];
  const float* A2     = (const float*)d_in[8];
  const float* B2     = (const float*)d_in[9];
  const float* W2     = (const float*)d_in[10];
  const float* attL2  = (const float*)d_in[11];
  const float* attR2  = (const float*)d_in[12];
  const float* relb2  = (const float*)d_in[13];
  const float* bias2  = (const float*)d_in[14];
  const float* res_W  = (const float*)d_in[15];
  const float* res_b  = (const float*)d_in[16];
  const float* ln_g   = (const float*)d_in[17];
  const float* ln_b   = (const float*)d_in[18];
  const int*   eidx   = (const int*)d_in[19];
  const int*   etype  = (const int*)d_in[20];
  float* out = (float*)d_out;

  const int Nn = in_sizes[0] / EMB;     // 30000
  const int E  = in_sizes[20];          // 150000
  const int* ji = eidx;
  const int* ii = eidx + E;

  // ---- workspace carve-up ----
  float* w = (float*)d_ws;
  size_t off = 0;
  float* z1    = w + off; off += (size_t)Nn * D2;
  float* z2    = w + off; off += (size_t)Nn * OUTD;
  float* o2    = w + off; off += (size_t)Nn * OUTD;
  float* P1    = w + off; off += (size_t)Nn * 64;
  float* P2    = w + off; off += (size_t)Nn * 64;
  float* M1    = w + off; off += 64 * D2;
  float* M2    = w + off; off += 64 * OUTD;
  float* Amat1 = w + off; off += 64 * EMB;
  float* Amat2 = w + off; off += 64 * D2;
  float* Matt1 = w + off; off += 64 * 4;
  float* Matt2 = w + off; off += 64;
  float* al1   = w + off; off += (size_t)Nn * 4;
  float* ar1   = w + off; off += (size_t)Nn * 4;
  float* al2   = w + off; off += (size_t)Nn;
  float* ar2   = w + off; off += (size_t)Nn;
  float* ex1   = w + off; off += (size_t)E * 4;
  float* ex2   = w + off; off += (size_t)E;
  unsigned short* x0b    = (unsigned short*)(w + off); off += (size_t)Nn * EMB / 2;
  unsigned short* h1b    = (unsigned short*)(w + off); off += (size_t)Nn * D2 / 2;
  unsigned short* W1b    = (unsigned short*)(w + off); off += (size_t)D2 * EMB / 2;
  unsigned short* W2b    = (unsigned short*)(w + off); off += (size_t)OUTD * D2 / 2;
  unsigned short* resWb  = (unsigned short*)(w + off); off += (size_t)OUTD * EMB / 2;
  unsigned short* Bmat1b = (unsigned short*)(w + off); off += (size_t)64 * EMB / 2;
  unsigned short* Bmat2b = (unsigned short*)(w + off); off += (size_t)64 * D2 / 2;
  int* ideg     = (int*)(w + off); off += (size_t)Nn;
  int* rowstart = (int*)(w + off); off += (size_t)Nn + 1;
  int* cursor   = (int*)(w + off); off += (size_t)Nn;
  int* eid      = (int*)(w + off); off += (size_t)E;
  (void)ws_size; (void)n_in; (void)out_size;

  const int MT64 = (Nn + 63) / 64;     // 469
  const int MT128 = (Nn + 127) / 128;  // 235

  // 0) CSR build
  (void)hipMemsetAsync(ideg, 0, (size_t)Nn * sizeof(int), stream);
  (void)hipMemsetAsync(cursor, 0, (size_t)Nn * sizeof(int), stream);
  hist_kernel<<<(E + 255) / 256, 256, 0, stream>>>(ii, ideg, E);
  exscan_kernel<<<1, 1024, 0, stream>>>(ideg, rowstart, Nn);
  scatter_kernel<<<(E + 255) / 256, 256, 0, stream>>>(ii, rowstart, cursor, eid, E);

  // 1) LoRA re-layouts
  expand_lora<<<(64 * EMB + 255) / 256, 256, 0, stream>>>(A1, Amat1, NRELS, EMB);
  expand_lora<<<(64 * D2 + 255) / 256, 256, 0, stream>>>(A2, Amat2, NRELS, D2);
  expand_lora_bf16<<<(64 * EMB + 255) / 256, 256, 0, stream>>>(B1, Bmat1b, NRELS, EMB);
  expand_lora_bf16<<<(64 * D2 + 255) / 256, 256, 0, stream>>>(B2, Bmat2b, NRELS, D2);

  // 2) bf16 conversions
  to_bf16<<<(Nn * EMB + 255) / 256, 256, 0, stream>>>(x0, x0b, Nn * EMB);
  to_bf16<<<(D2 * EMB + 255) / 256, 256, 0, stream>>>(W1, W1b, D2 * EMB);
  to_bf16<<<(OUTD * D2 + 255) / 256, 256, 0, stream>>>(W2, W2b, OUTD * D2);
  to_bf16<<<(OUTD * EMB + 255) / 256, 256, 0, stream>>>(res_W, resWb, OUTD * EMB);

  // 3) M1 = Amat1 @ W1^T ; M2 = Amat2 @ W2^T  (fp32, tiny)
  gemm_abt<<<dim3(D2 / 64, 1), 256, 0, stream>>>(Amat1, W1, M1, 64, D2, EMB);
  gemm_abt<<<dim3(OUTD / 64, 1), 256, 0, stream>>>(Amat2, W2, M2, 64, OUTD, D2);
  matt1_kernel<<<1, 256, 0, stream>>>(M1, attR1, Matt1);
  matt2_kernel<<<1, 64, 0, stream>>>(M2, attR2, Matt2);

  // 4) Layer-1 node GEMMs (big-tile MFMA for z1; 64-tile for P1)
  gemm_big<<<dim3(MT128, D2 / 128), 256, 0, stream>>>(x0b, W1b, z1, Nn, D2, EMB);
  gemm_bf16t<<<dim3(MT64, 1), 256, 0, stream>>>(x0b, Bmat1b, P1, Nn, 64, EMB);

  // 5) attention dots
  rowdot<<<(Nn * 4 + 255) / 256, 256, 0, stream>>>(z1, attL1, attR1, al1, ar1, Nn, HEADS, HID);

  // 6) Layer-1 edge logits + CSR gather
  edge_alpha1<<<(E + 255) / 256, 256, 0, stream>>>(ji, ii, etype, P1, al1, ar1, relb1, Matt1,
                                                   ex1, E);
  node_agg1<<<Nn, 256, 0, stream>>>(ji, etype, rowstart, eid, P1, M1, ex1, z1, bias1, h1b, Nn);

  // 7) Layer-2 node GEMMs + residual
  gemm_big<<<dim3(MT128, OUTD / 128), 256, 0, stream>>>(h1b, W2b, z2, Nn, OUTD, D2);
  gemm_bf16t<<<dim3(MT64, 1), 256, 0, stream>>>(h1b, Bmat2b, P2, Nn, 64, D2);
  gemm_big<<<dim3(MT128, OUTD / 128), 256, 0, stream>>>(x0b, resWb, o2, Nn, OUTD, EMB);

  // 8) Layer-2 attention dots
  rowdot<<<(Nn + 255) / 256, 256, 0, stream>>>(z2, attL2, attR2, al2, ar2, Nn, 1, OUTD);

  // 9) Layer-2 edge logits + CSR gather (fused residual/bias/LN)
  edge_alpha2<<<(E + 255) / 256, 256, 0, stream>>>(ji, ii, etype, P2, al2, ar2, relb2, Matt2,
                                                   ex2, E);
  node_agg2<<<Nn, 256, 0, stream>>>(ji, etype, rowstart, eid, P2, M2, ex2, z2, o2,
                                    bias2, res_b, ln_g, ln_b, out, Nn);
}